// Round 1
// baseline (2506.362 us; speedup 1.0000x reference)
//
#include <hip/hip_runtime.h>
#include <math.h>

#define D_STATE 16
#define D_INNER 2048
#define SEQ     2048
#define BSZ     2
#define NTOK    (BSZ*SEQ)   // 4096

// ---------------------------------------------------------------------------
// GEMM: C[m,n] = sum_k A[m*lda+k] * W[n*K+k]
// MODE 0: plain   MODE 1: softplus(acc + aux[n])   MODE 2: acc + aux[m*ldc+n]
// 64x64 tile, 256 threads, 4x4 micro-tile, K-tile=16, LDS k-major (pad->68)
// ---------------------------------------------------------------------------
template<int MODE>
__global__ __launch_bounds__(256) void gemm_k(
    const float* __restrict__ A, int lda,
    const float* __restrict__ W,
    float* __restrict__ C, int ldc,
    int M, int N, int K,
    const float* __restrict__ aux)
{
  __shared__ float As[16][68];
  __shared__ float Ws[16][68];
  const int tid = threadIdx.x;
  const int tx = tid & 15, ty = tid >> 4;
  const int m0 = blockIdx.y * 64, n0 = blockIdx.x * 64;
  float acc[4][4] = {};

  for (int kt = 0; kt < K; kt += 16) {
#pragma unroll
    for (int r = 0; r < 4; ++r) {
      int idx = tid + r * 256;        // 0..1023
      int mm = idx >> 4, kk = idx & 15;
      As[kk][mm] = A[(size_t)(m0 + mm) * lda + kt + kk];   // M always 4096, full
      float wv = 0.f;
      if (n0 + mm < N) wv = W[(size_t)(n0 + mm) * K + kt + kk];
      Ws[kk][mm] = wv;
    }
    __syncthreads();
#pragma unroll
    for (int kk = 0; kk < 16; ++kk) {
      float4 a = *(const float4*)&As[kk][ty * 4];
      float4 b = *(const float4*)&Ws[kk][tx * 4];
      float av[4] = {a.x, a.y, a.z, a.w};
      float bv[4] = {b.x, b.y, b.z, b.w};
#pragma unroll
      for (int i = 0; i < 4; ++i)
#pragma unroll
        for (int j = 0; j < 4; ++j)
          acc[i][j] = fmaf(av[i], bv[j], acc[i][j]);
    }
    __syncthreads();
  }

#pragma unroll
  for (int i = 0; i < 4; ++i) {
    int m = m0 + ty * 4 + i;
#pragma unroll
    for (int j = 0; j < 4; ++j) {
      int n = n0 + tx * 4 + j;
      if (n < N) {
        float v = acc[i][j];
        if (MODE == 1) { v += aux[n]; v = (v > 20.f) ? v : log1pf(expf(v)); }
        if (MODE == 2) { v += aux[(size_t)m * ldc + n]; }
        C[(size_t)m * ldc + n] = v;
      }
    }
  }
}

// ---------------------------------------------------------------------------
// Depthwise causal conv(4) + bias + SiLU.  Input = xi half of xz (stride 4096).
// ---------------------------------------------------------------------------
__global__ __launch_bounds__(256) void conv_silu_k(
    const float* __restrict__ xz, const float* __restrict__ w,
    const float* __restrict__ b, float* __restrict__ xc)
{
  int idx = blockIdx.x * 256 + threadIdx.x;   // over NTOK*D_INNER
  int e  = idx & (D_INNER - 1);
  int bl = idx >> 11;                          // b*SEQ + l
  int l  = bl & (SEQ - 1);
  float acc = b[e];
#pragma unroll
  for (int k = 0; k < 4; ++k) {
    int ll = l - 3 + k;
    if (ll >= 0)
      acc = fmaf(xz[(size_t)(bl + ll - l) * 4096 + e], w[e * 4 + k], acc);
  }
  xc[idx] = acc / (1.f + expf(-acc));          // silu
}

// ---------------------------------------------------------------------------
// Selective scan. 16 lanes per (b,d) channel: lane = state s.
// dt_y: read dt, overwrite with gated y (same element, safe in-wave).
// ---------------------------------------------------------------------------
__global__ __launch_bounds__(256) void scan_k(
    const float* __restrict__ A_log, const float* __restrict__ Dvec,
    const float* __restrict__ x_dbl, const float* __restrict__ xc,
    const float* __restrict__ xz, float* dt_y)
{
  const int g = threadIdx.x >> 4;
  const int s = threadIdx.x & 15;
  const int c = blockIdx.x * 16 + g;     // 0..4095
  const int b = c >> 11;
  const int d = c & 2047;
  const float Ac = -expf(A_log[d * 16 + s]);
  const float Dd = Dvec[d];
  const float* xd = x_dbl + (size_t)b * SEQ * 96;
  float h = 0.f;

  size_t base = (size_t)b * SEQ;
  // prefetch l=0
  float dtv = dt_y[base * 2048 + d];
  float u   = xc[base * 2048 + d];
  float Bs  = xd[64 + s];
  float Cs  = xd[80 + s];

  for (int l = 0; l < SEQ; ++l) {
    float dtv_n = 0.f, u_n = 0.f, Bs_n = 0.f, Cs_n = 0.f;
    if (l + 1 < SEQ) {
      size_t bn = base + l + 1;
      dtv_n = dt_y[bn * 2048 + d];
      u_n   = xc[bn * 2048 + d];
      Bs_n  = xd[(l + 1) * 96 + 64 + s];
      Cs_n  = xd[(l + 1) * 96 + 80 + s];
    }
    float dA = expf(dtv * Ac);
    h = fmaf(dA, h, dtv * u * Bs);
    float p = h * Cs;
    p += __shfl_xor(p, 1, 16);
    p += __shfl_xor(p, 2, 16);
    p += __shfl_xor(p, 4, 16);
    p += __shfl_xor(p, 8, 16);
    if (s == 0) {
      size_t bi = base + l;
      float zv = xz[bi * 4096 + 2048 + d];
      float yv = fmaf(Dd, u, p);
      yv *= zv / (1.f + expf(-zv));
      dt_y[bi * 2048 + d] = yv;
    }
    dtv = dtv_n; u = u_n; Bs = Bs_n; Cs = Cs_n;
  }
}

// ---------------------------------------------------------------------------
// LayerNorm over 1024, one block (256 thr) per row.
// ---------------------------------------------------------------------------
__global__ __launch_bounds__(256) void ln_k(
    const float* __restrict__ t, const float* __restrict__ g,
    const float* __restrict__ bb, float* __restrict__ out)
{
  int row = blockIdx.x;
  float4 v = ((const float4*)(t + (size_t)row * 1024))[threadIdx.x];
  float s  = v.x + v.y + v.z + v.w;
  float sq = v.x * v.x + v.y * v.y + v.z * v.z + v.w * v.w;
#pragma unroll
  for (int off = 32; off >= 1; off >>= 1) {
    s  += __shfl_xor(s,  off, 64);
    sq += __shfl_xor(sq, off, 64);
  }
  __shared__ float red[8];
  int wid = threadIdx.x >> 6;
  if ((threadIdx.x & 63) == 0) { red[wid] = s; red[4 + wid] = sq; }
  __syncthreads();
  s  = red[0] + red[1] + red[2] + red[3];
  sq = red[4] + red[5] + red[6] + red[7];
  float mu  = s * (1.f / 1024.f);
  float var = sq * (1.f / 1024.f) - mu * mu;
  float r   = rsqrtf(var + 1e-5f);
  int col = threadIdx.x * 4;
  float4 gv = *(const float4*)(g + col);
  float4 bv = *(const float4*)(bb + col);
  float4 o;
  o.x = (v.x - mu) * r * gv.x + bv.x;
  o.y = (v.y - mu) * r * gv.y + bv.y;
  o.z = (v.z - mu) * r * gv.z + bv.z;
  o.w = (v.w - mu) * r * gv.w + bv.w;
  ((float4*)(out + (size_t)row * 1024))[threadIdx.x] = o;
}

// ---------------------------------------------------------------------------
extern "C" void kernel_launch(void* const* d_in, const int* in_sizes, int n_in,
                              void* d_out, int out_size, void* d_ws, size_t ws_size,
                              hipStream_t stream)
{
  const float* x       = (const float*)d_in[0];
  const float* in_proj = (const float*)d_in[1];
  const float* conv_w  = (const float*)d_in[2];
  const float* conv_b  = (const float*)d_in[3];
  const float* x_proj  = (const float*)d_in[4];
  const float* dt_w    = (const float*)d_in[5];
  const float* dt_b    = (const float*)d_in[6];
  const float* A_log   = (const float*)d_in[7];
  const float* Dv      = (const float*)d_in[8];
  const float* out_w   = (const float*)d_in[9];
  const float* ln_g    = (const float*)d_in[10];
  const float* ln_bias = (const float*)d_in[11];
  float* out = (float*)d_out;

  float* ws   = (float*)d_ws;
  float* xz   = ws;                              // 4096*4096
  float* xc   = xz   + (size_t)NTOK * 4096;      // 4096*2048
  float* xdbl = xc   + (size_t)NTOK * 2048;      // 4096*96
  float* dty  = xdbl + (size_t)NTOK * 96;        // 4096*2048 (dt, then y in-place)
  float* tmp  = xz;                              // reuse xz space for pre-LN

  dim3 blk(256);
  // 1) in_proj: (4096x1024)@(4096x1024)^T -> xz (4096x4096)
  gemm_k<0><<<dim3(64, 64), blk, 0, stream>>>(x, 1024, in_proj, xz, 4096,
                                              NTOK, 4096, 1024, nullptr);
  // 2) conv + silu -> xc
  conv_silu_k<<<dim3((NTOK * D_INNER) / 256), blk, 0, stream>>>(xz, conv_w, conv_b, xc);
  // 3) x_proj: -> x_dbl (4096x96)
  gemm_k<0><<<dim3(2, 64), blk, 0, stream>>>(xc, 2048, x_proj, xdbl, 96,
                                             NTOK, 96, 2048, nullptr);
  // 4) dt_proj + softplus: K=64 (dt_r = first 64 cols of x_dbl, lda=96)
  gemm_k<1><<<dim3(32, 64), blk, 0, stream>>>(xdbl, 96, dt_w, dty, 2048,
                                              NTOK, 2048, 64, dt_b);
  // 5) selective scan (+ D*u, * silu(z)) -> y in-place over dt
  scan_k<<<dim3(256), blk, 0, stream>>>(A_log, Dv, xdbl, xc, xz, dty);
  // 6) out_proj + residual x -> tmp
  gemm_k<2><<<dim3(16, 64), blk, 0, stream>>>(dty, 2048, out_w, tmp, 1024,
                                              NTOK, 1024, 2048, x);
  // 7) layernorm -> out
  ln_k<<<dim3(NTOK), blk, 0, stream>>>(tmp, ln_g, ln_bias, out);
}

// Round 2
// 1522.820 us; speedup vs baseline: 1.6459x; 1.6459x over previous
//
#include <hip/hip_runtime.h>
#include <math.h>

#define D_STATE 16
#define D_INNER 2048
#define SEQ     2048
#define BSZ     2
#define NTOK    (BSZ*SEQ)   // 4096
#define CH      128          // scan chunk length
#define NCHK    (SEQ/CH)     // 16 chunks per sequence

// ---------------------------------------------------------------------------
// GEMM: C[m,n] = sum_k A[m*lda+k] * W[n*K+k]
// MODE 0: plain   MODE 1: softplus(acc + aux[n])   MODE 2: acc + aux[m*ldc+n]
// 64x64 tile, 256 threads, 4x4 micro-tile, K-tile=16, LDS k-major (pad->68)
// ---------------------------------------------------------------------------
template<int MODE>
__global__ __launch_bounds__(256) void gemm_k(
    const float* __restrict__ A, int lda,
    const float* __restrict__ W,
    float* __restrict__ C, int ldc,
    int M, int N, int K,
    const float* __restrict__ aux)
{
  __shared__ float As[16][68];
  __shared__ float Ws[16][68];
  const int tid = threadIdx.x;
  const int tx = tid & 15, ty = tid >> 4;
  const int m0 = blockIdx.y * 64, n0 = blockIdx.x * 64;
  float acc[4][4] = {};

  for (int kt = 0; kt < K; kt += 16) {
#pragma unroll
    for (int r = 0; r < 4; ++r) {
      int idx = tid + r * 256;        // 0..1023
      int mm = idx >> 4, kk = idx & 15;
      As[kk][mm] = A[(size_t)(m0 + mm) * lda + kt + kk];   // M always 4096, full
      float wv = 0.f;
      if (n0 + mm < N) wv = W[(size_t)(n0 + mm) * K + kt + kk];
      Ws[kk][mm] = wv;
    }
    __syncthreads();
#pragma unroll
    for (int kk = 0; kk < 16; ++kk) {
      float4 a = *(const float4*)&As[kk][ty * 4];
      float4 b = *(const float4*)&Ws[kk][tx * 4];
      float av[4] = {a.x, a.y, a.z, a.w};
      float bv[4] = {b.x, b.y, b.z, b.w};
#pragma unroll
      for (int i = 0; i < 4; ++i)
#pragma unroll
        for (int j = 0; j < 4; ++j)
          acc[i][j] = fmaf(av[i], bv[j], acc[i][j]);
    }
    __syncthreads();
  }

#pragma unroll
  for (int i = 0; i < 4; ++i) {
    int m = m0 + ty * 4 + i;
#pragma unroll
    for (int j = 0; j < 4; ++j) {
      int n = n0 + tx * 4 + j;
      if (n < N) {
        float v = acc[i][j];
        if (MODE == 1) { v += aux[n]; v = (v > 20.f) ? v : log1pf(expf(v)); }
        if (MODE == 2) { v += aux[(size_t)m * ldc + n]; }
        C[(size_t)m * ldc + n] = v;
      }
    }
  }
}

// ---------------------------------------------------------------------------
// Depthwise causal conv(4) + bias + SiLU.  Input = xi half of xz (stride 4096).
// ---------------------------------------------------------------------------
__global__ __launch_bounds__(256) void conv_silu_k(
    const float* __restrict__ xz, const float* __restrict__ w,
    const float* __restrict__ b, float* __restrict__ xc)
{
  int idx = blockIdx.x * 256 + threadIdx.x;   // over NTOK*D_INNER
  int e  = idx & (D_INNER - 1);
  int bl = idx >> 11;                          // b*SEQ + l
  int l  = bl & (SEQ - 1);
  float acc = b[e];
#pragma unroll
  for (int k = 0; k < 4; ++k) {
    int ll = l - 3 + k;
    if (ll >= 0)
      acc = fmaf(xz[(size_t)(bl + ll - l) * 4096 + e], w[e * 4 + k], acc);
  }
  xc[idx] = acc / (1.f + expf(-acc));          // silu
}

// ---------------------------------------------------------------------------
// Chunked selective scan.
// Work unit = (b, chunk, d); 16 lanes per unit (lane = state s).
// unit = (b*NCHK + c)*2048 + d   (consecutive units share chunk -> B/C L1 reuse)
// P/Hl fix-up buffers (4 MB each) live in the dead xi half of xz:
//   flat idx -> row-carved address  (xi region = columns 0..2047 of xz rows)
// ---------------------------------------------------------------------------
__device__ __forceinline__ size_t carve(int idx) {
  return ((size_t)(idx >> 11)) * 4096 + (idx & 2047);
}

__global__ __launch_bounds__(256) void scan_p1(
    const float* __restrict__ A_log,
    const float* __restrict__ x_dbl, const float* __restrict__ xc,
    const float* __restrict__ dt, float* __restrict__ xz /*P,Hl carve*/)
{
  const int unit = blockIdx.x * 16 + (threadIdx.x >> 4);
  const int s = threadIdx.x & 15;
  const int d = unit & 2047;
  const int c = (unit >> 11) & (NCHK - 1);
  const int b = unit >> 15;
  const float Ac = -expf(A_log[d * 16 + s]);
  const size_t base = ((size_t)b * SEQ + c * CH) * 2048 + d;   // + l*2048
  const float* xd = x_dbl + ((size_t)b * SEQ + c * CH) * 96;

  float p = 1.f, h = 0.f;
#pragma unroll 4
  for (int l = 0; l < CH; ++l) {
    float dtv = dt[base + (size_t)l * 2048];
    float uv  = xc[base + (size_t)l * 2048];
    float Bs  = xd[l * 96 + 64 + s];
    float dA  = expf(dtv * Ac);
    p *= dA;
    h = fmaf(dA, h, dtv * uv * Bs);
  }
  int idx = unit * 16 + s;
  xz[carve(idx)] = p;                       // P
  xz[carve(idx) + (size_t)512 * 4096] = h;  // Hl
}

// Sequential fix-up over chunks: overwrite Hl[c] with chunk-entry state hin[c].
__global__ __launch_bounds__(256) void scan_fix(float* __restrict__ xz)
{
  int tid = blockIdx.x * 256 + threadIdx.x;  // (b*2048+d)*16+s
  int s = tid & 15;
  int d = (tid >> 4) & 2047;
  int b = tid >> 15;
  float h = 0.f;
  for (int c = 0; c < NCHK; ++c) {
    int idx = (((b * NCHK + c) * 2048) + d) * 16 + s;
    float p  = xz[carve(idx)];
    size_t ha = carve(idx) + (size_t)512 * 4096;
    float hl = xz[ha];
    xz[ha] = h;               // hin for chunk c
    h = fmaf(p, h, hl);
  }
}

__global__ __launch_bounds__(256) void scan_p2(
    const float* __restrict__ A_log, const float* __restrict__ Dvec,
    const float* __restrict__ x_dbl, const float* __restrict__ xc,
    const float* __restrict__ xz, float* __restrict__ dt_y)
{
  const int unit = blockIdx.x * 16 + (threadIdx.x >> 4);
  const int s = threadIdx.x & 15;
  const int d = unit & 2047;
  const int c = (unit >> 11) & (NCHK - 1);
  const int b = unit >> 15;
  const float Ac = -expf(A_log[d * 16 + s]);
  const float Dd = Dvec[d];
  const size_t base = ((size_t)b * SEQ + c * CH) * 2048 + d;
  const float* xd = x_dbl + ((size_t)b * SEQ + c * CH) * 96;

  float h = xz[carve(unit * 16 + s) + (size_t)512 * 4096];  // hin
#pragma unroll 2
  for (int l = 0; l < CH; ++l) {
    float dtv = dt_y[base + (size_t)l * 2048];
    float uv  = xc[base + (size_t)l * 2048];
    float Bs  = xd[l * 96 + 64 + s];
    float Cs  = xd[l * 96 + 80 + s];
    float dA  = expf(dtv * Ac);
    h = fmaf(dA, h, dtv * uv * Bs);
    float pr = h * Cs;
    pr += __shfl_xor(pr, 1, 16);
    pr += __shfl_xor(pr, 2, 16);
    pr += __shfl_xor(pr, 4, 16);
    pr += __shfl_xor(pr, 8, 16);
    if (s == 0) {
      float zv = xz[base + (size_t)l * 2048 + base * 0 + 2048 - d + ((size_t)b * SEQ + c * CH + l) * 4096 - ((size_t)b * SEQ + c * CH + l) * 4096];
      // z = xz[(b*SEQ + c*CH + l)*4096 + 2048 + d] — computed cleanly below
      zv = xz[((size_t)b * SEQ + c * CH + l) * 4096 + 2048 + d];
      float yv = fmaf(Dd, uv, pr);
      yv *= zv / (1.f + expf(-zv));
      dt_y[base + (size_t)l * 2048] = yv;
    }
  }
}

// ---------------------------------------------------------------------------
// LayerNorm over 1024, one block (256 thr) per row.
// ---------------------------------------------------------------------------
__global__ __launch_bounds__(256) void ln_k(
    const float* __restrict__ t, const float* __restrict__ g,
    const float* __restrict__ bb, float* __restrict__ out)
{
  int row = blockIdx.x;
  float4 v = ((const float4*)(t + (size_t)row * 1024))[threadIdx.x];
  float s  = v.x + v.y + v.z + v.w;
  float sq = v.x * v.x + v.y * v.y + v.z * v.z + v.w * v.w;
#pragma unroll
  for (int off = 32; off >= 1; off >>= 1) {
    s  += __shfl_xor(s,  off, 64);
    sq += __shfl_xor(sq, off, 64);
  }
  __shared__ float red[8];
  int wid = threadIdx.x >> 6;
  if ((threadIdx.x & 63) == 0) { red[wid] = s; red[4 + wid] = sq; }
  __syncthreads();
  s  = red[0] + red[1] + red[2] + red[3];
  sq = red[4] + red[5] + red[6] + red[7];
  float mu  = s * (1.f / 1024.f);
  float var = sq * (1.f / 1024.f) - mu * mu;
  float r   = rsqrtf(var + 1e-5f);
  int col = threadIdx.x * 4;
  float4 gv = *(const float4*)(g + col);
  float4 bv = *(const float4*)(bb + col);
  float4 o;
  o.x = (v.x - mu) * r * gv.x + bv.x;
  o.y = (v.y - mu) * r * gv.y + bv.y;
  o.z = (v.z - mu) * r * gv.z + bv.z;
  o.w = (v.w - mu) * r * gv.w + bv.w;
  ((float4*)(out + (size_t)row * 1024))[threadIdx.x] = o;
}

// ---------------------------------------------------------------------------
extern "C" void kernel_launch(void* const* d_in, const int* in_sizes, int n_in,
                              void* d_out, int out_size, void* d_ws, size_t ws_size,
                              hipStream_t stream)
{
  const float* x       = (const float*)d_in[0];
  const float* in_proj = (const float*)d_in[1];
  const float* conv_w  = (const float*)d_in[2];
  const float* conv_b  = (const float*)d_in[3];
  const float* x_proj  = (const float*)d_in[4];
  const float* dt_w    = (const float*)d_in[5];
  const float* dt_b    = (const float*)d_in[6];
  const float* A_log   = (const float*)d_in[7];
  const float* Dv      = (const float*)d_in[8];
  const float* out_w   = (const float*)d_in[9];
  const float* ln_g    = (const float*)d_in[10];
  const float* ln_bias = (const float*)d_in[11];
  float* out = (float*)d_out;

  float* ws   = (float*)d_ws;
  float* xz   = ws;                              // 4096*4096 (xi half reused for P/Hl)
  float* xc   = xz   + (size_t)NTOK * 4096;      // 4096*2048
  float* xdbl = xc   + (size_t)NTOK * 2048;      // 4096*96
  float* dty  = xdbl + (size_t)NTOK * 96;        // 4096*2048 (dt, then y in-place)
  float* tmp  = xz;                              // reuse xz space for pre-LN

  dim3 blk(256);
  // 1) in_proj: (4096x1024)@(4096x1024)^T -> xz (4096x4096)
  gemm_k<0><<<dim3(64, 64), blk, 0, stream>>>(x, 1024, in_proj, xz, 4096,
                                              NTOK, 4096, 1024, nullptr);
  // 2) conv + silu -> xc   (xi half of xz is DEAD after this; P/Hl carve into it)
  conv_silu_k<<<dim3((NTOK * D_INNER) / 256), blk, 0, stream>>>(xz, conv_w, conv_b, xc);
  // 3) x_proj: -> x_dbl (4096x96)
  gemm_k<0><<<dim3(2, 64), blk, 0, stream>>>(xc, 2048, x_proj, xdbl, 96,
                                             NTOK, 96, 2048, nullptr);
  // 4) dt_proj + softplus: K=64 (dt_r = first 64 cols of x_dbl, lda=96)
  gemm_k<1><<<dim3(32, 64), blk, 0, stream>>>(xdbl, 96, dt_w, dty, 2048,
                                              NTOK, 2048, 64, dt_b);
  // 5) chunked selective scan -> y in-place over dt
  scan_p1 <<<dim3(BSZ * NCHK * 2048 / 16), blk, 0, stream>>>(A_log, xdbl, xc, dty, xz);
  scan_fix<<<dim3(BSZ * 2048 * 16 / 256), blk, 0, stream>>>(xz);
  scan_p2 <<<dim3(BSZ * NCHK * 2048 / 16), blk, 0, stream>>>(A_log, Dv, xdbl, xc, xz, dty);
  // 6) out_proj + residual x -> tmp
  gemm_k<2><<<dim3(16, 64), blk, 0, stream>>>(dty, 2048, out_w, tmp, 1024,
                                              NTOK, 1024, 2048, x);
  // 7) layernorm -> out
  ln_k<<<dim3(NTOK), blk, 0, stream>>>(tmp, ln_g, ln_bias, out);
}

// Round 3
// 656.653 us; speedup vs baseline: 3.8169x; 2.3191x over previous
//
#include <hip/hip_runtime.h>
#include <math.h>

#define D_STATE 16
#define D_INNER 2048
#define SEQ     2048
#define BSZ     2
#define NTOK    (BSZ*SEQ)   // 4096
#define CH      128          // scan chunk length
#define NCHK    (SEQ/CH)     // 16 chunks per sequence

typedef __bf16 bf16x8 __attribute__((ext_vector_type(8)));
typedef float  floatx4 __attribute__((ext_vector_type(4)));

__device__ __forceinline__ unsigned short f2bf(float f) {  // RNE fp32->bf16
  unsigned int u = __float_as_uint(f);
  u += 0x7fff + ((u >> 16) & 1);
  return (unsigned short)(u >> 16);
}

__device__ __forceinline__ void gload16(const unsigned short* g, unsigned short* l) {
  __builtin_amdgcn_global_load_lds(
      (const __attribute__((address_space(1))) unsigned int*)g,
      (__attribute__((address_space(3))) unsigned int*)l, 16, 0, 0);
}

// ---------------------------------------------------------------------------
// fp32 -> bf16 cast, 4 elems/thread. n must be divisible by 1024.
// ---------------------------------------------------------------------------
__global__ __launch_bounds__(256) void cast_k(
    const float* __restrict__ src, unsigned short* __restrict__ dst, int n)
{
  int i = (blockIdx.x * 256 + threadIdx.x) * 4;
  if (i < n) {
    float4 v = *(const float4*)(src + i);
    ushort4 o;
    o.x = f2bf(v.x); o.y = f2bf(v.y); o.z = f2bf(v.z); o.w = f2bf(v.w);
    *(ushort4*)(dst + i) = o;
  }
}

// ---------------------------------------------------------------------------
// bf16 MFMA GEMM: C[m,n] = sum_k A[m,k]*W[n,k]  (fp32 accumulate/output)
// 128x128 tile, 256 thr (4 waves), 4x4 16x16x32 frags/wave, BK=32,
// global_load_lds width-16 staging (m97 structure). M multiple of 128,
// K multiple of 32; N ragged handled by clamp (stage) + guard (store).
// MODE 0: plain   MODE 2: + aux[m*ldc+n] (residual)
// ---------------------------------------------------------------------------
template<int MODE>
__global__ __launch_bounds__(256) void mgemm(
    const unsigned short* __restrict__ A, int lda,
    const unsigned short* __restrict__ W, int ldw,
    float* __restrict__ C, int ldc,
    int N, int K, const float* __restrict__ aux)
{
  __shared__ unsigned short As[128 * 32];
  __shared__ unsigned short Ws[128 * 32];
  const int tid  = threadIdx.x;
  const int wave = tid >> 6, lane = tid & 63;
  const int m0 = blockIdx.y * 128, n0 = blockIdx.x * 128;
  // staging: chunk = wave*2+j covers rows chunk*16..+15; lane -> (row, 8-elem col)
  const int srow = lane >> 2, scol = (lane & 3) * 8;
  // fragment coords
  const int fr = lane & 15, fq = lane >> 4;
  const int wm = (wave >> 1) * 64, wn = (wave & 1) * 64;

  const int ar0 = (wave * 2 + 0) * 16 + srow;
  const int ar1 = (wave * 2 + 1) * 16 + srow;
  int wr0 = n0 + ar0; if (wr0 > N - 1) wr0 = N - 1;
  int wr1 = n0 + ar1; if (wr1 > N - 1) wr1 = N - 1;
  const unsigned short* gA0 = A + (size_t)(m0 + ar0) * lda + scol;
  const unsigned short* gA1 = A + (size_t)(m0 + ar1) * lda + scol;
  const unsigned short* gW0 = W + (size_t)wr0 * ldw + scol;
  const unsigned short* gW1 = W + (size_t)wr1 * ldw + scol;
  unsigned short* lA0 = As + (wave * 2 + 0) * 512;
  unsigned short* lA1 = As + (wave * 2 + 1) * 512;
  unsigned short* lW0 = Ws + (wave * 2 + 0) * 512;
  unsigned short* lW1 = Ws + (wave * 2 + 1) * 512;

  floatx4 zero = {0.f, 0.f, 0.f, 0.f};
  floatx4 acc[4][4];
#pragma unroll
  for (int i = 0; i < 4; ++i)
#pragma unroll
    for (int j = 0; j < 4; ++j) acc[i][j] = zero;

  for (int kt = 0; kt < K; kt += 32) {
    __syncthreads();
    gload16(gA0 + kt, lA0);
    gload16(gA1 + kt, lA1);
    gload16(gW0 + kt, lW0);
    gload16(gW1 + kt, lW1);
    __syncthreads();
    bf16x8 af[4], bfr[4];
#pragma unroll
    for (int i = 0; i < 4; ++i) {
      af[i]  = *(const bf16x8*)(As + (wm + i * 16 + fr) * 32 + fq * 8);
      bfr[i] = *(const bf16x8*)(Ws + (wn + i * 16 + fr) * 32 + fq * 8);
    }
#pragma unroll
    for (int i = 0; i < 4; ++i)
#pragma unroll
      for (int j = 0; j < 4; ++j)
        acc[i][j] = __builtin_amdgcn_mfma_f32_16x16x32_bf16(af[i], bfr[j], acc[i][j], 0, 0, 0);
  }

  // C/D layout: col = lane&15, row = (lane>>4)*4 + reg
#pragma unroll
  for (int i = 0; i < 4; ++i) {
#pragma unroll
    for (int j = 0; j < 4; ++j) {
      int n = n0 + wn + j * 16 + fr;
      if (n < N) {
#pragma unroll
        for (int r = 0; r < 4; ++r) {
          int m = m0 + wm + i * 16 + fq * 4 + r;
          float v = acc[i][j][r];
          if (MODE == 2) v += aux[(size_t)m * ldc + n];
          C[(size_t)m * ldc + n] = v;
        }
      }
    }
  }
}

// ---------------------------------------------------------------------------
// fp32 GEMM (kept for dt_proj, K=64): softplus(acc + aux[n])
// ---------------------------------------------------------------------------
__global__ __launch_bounds__(256) void gemm_sp(
    const float* __restrict__ A, int lda,
    const float* __restrict__ W,
    float* __restrict__ C, int ldc,
    int N, int K, const float* __restrict__ aux)
{
  __shared__ float As[16][68];
  __shared__ float Ws[16][68];
  const int tid = threadIdx.x;
  const int tx = tid & 15, ty = tid >> 4;
  const int m0 = blockIdx.y * 64, n0 = blockIdx.x * 64;
  float acc[4][4] = {};

  for (int kt = 0; kt < K; kt += 16) {
#pragma unroll
    for (int r = 0; r < 4; ++r) {
      int idx = tid + r * 256;
      int mm = idx >> 4, kk = idx & 15;
      As[kk][mm] = A[(size_t)(m0 + mm) * lda + kt + kk];
      float wv = 0.f;
      if (n0 + mm < N) wv = W[(size_t)(n0 + mm) * K + kt + kk];
      Ws[kk][mm] = wv;
    }
    __syncthreads();
#pragma unroll
    for (int kk = 0; kk < 16; ++kk) {
      float4 a = *(const float4*)&As[kk][ty * 4];
      float4 b = *(const float4*)&Ws[kk][tx * 4];
      float av[4] = {a.x, a.y, a.z, a.w};
      float bv[4] = {b.x, b.y, b.z, b.w};
#pragma unroll
      for (int i = 0; i < 4; ++i)
#pragma unroll
        for (int j = 0; j < 4; ++j)
          acc[i][j] = fmaf(av[i], bv[j], acc[i][j]);
    }
    __syncthreads();
  }

#pragma unroll
  for (int i = 0; i < 4; ++i) {
    int m = m0 + ty * 4 + i;
#pragma unroll
    for (int j = 0; j < 4; ++j) {
      int n = n0 + tx * 4 + j;
      if (n < N) {
        float v = acc[i][j] + aux[n];
        v = (v > 20.f) ? v : log1pf(expf(v));
        C[(size_t)m * ldc + n] = v;
      }
    }
  }
}

// ---------------------------------------------------------------------------
// Depthwise causal conv(4) + bias + SiLU. Writes fp32 xc and bf16 xc_bf.
// ---------------------------------------------------------------------------
__global__ __launch_bounds__(256) void conv_silu_k(
    const float* __restrict__ xz, const float* __restrict__ w,
    const float* __restrict__ b, float* __restrict__ xc,
    unsigned short* __restrict__ xcb)
{
  int idx = blockIdx.x * 256 + threadIdx.x;   // over NTOK*D_INNER
  int e  = idx & (D_INNER - 1);
  int bl = idx >> 11;                          // b*SEQ + l
  int l  = bl & (SEQ - 1);
  float acc = b[e];
#pragma unroll
  for (int k = 0; k < 4; ++k) {
    int ll = l - 3 + k;
    if (ll >= 0)
      acc = fmaf(xz[(size_t)(bl + ll - l) * 4096 + e], w[e * 4 + k], acc);
  }
  float v = acc / (1.f + expf(-acc));          // silu
  xc[idx] = v;
  xcb[idx] = f2bf(v);
}

// ---------------------------------------------------------------------------
// Chunked selective scan (see round 1). P/Hl carved into dead xi half of xz.
// ---------------------------------------------------------------------------
__device__ __forceinline__ size_t carve(int idx) {
  return ((size_t)(idx >> 11)) * 4096 + (idx & 2047);
}

__global__ __launch_bounds__(256) void scan_p1(
    const float* __restrict__ A_log,
    const float* __restrict__ x_dbl, const float* __restrict__ xc,
    const float* __restrict__ dt, float* __restrict__ xz)
{
  const int unit = blockIdx.x * 16 + (threadIdx.x >> 4);
  const int s = threadIdx.x & 15;
  const int d = unit & 2047;
  const int c = (unit >> 11) & (NCHK - 1);
  const int b = unit >> 15;
  const float Ac = -expf(A_log[d * 16 + s]);
  const size_t base = ((size_t)b * SEQ + c * CH) * 2048 + d;
  const float* xd = x_dbl + ((size_t)b * SEQ + c * CH) * 96;

  float p = 1.f, h = 0.f;
#pragma unroll 4
  for (int l = 0; l < CH; ++l) {
    float dtv = dt[base + (size_t)l * 2048];
    float uv  = xc[base + (size_t)l * 2048];
    float Bs  = xd[l * 96 + 64 + s];
    float dA  = expf(dtv * Ac);
    p *= dA;
    h = fmaf(dA, h, dtv * uv * Bs);
  }
  int idx = unit * 16 + s;
  xz[carve(idx)] = p;                       // P
  xz[carve(idx) + (size_t)512 * 4096] = h;  // Hl
}

__global__ __launch_bounds__(256) void scan_fix(float* __restrict__ xz)
{
  int tid = blockIdx.x * 256 + threadIdx.x;  // (b*2048+d)*16+s
  int s = tid & 15;
  int d = (tid >> 4) & 2047;
  int b = tid >> 15;
  float h = 0.f;
  for (int c = 0; c < NCHK; ++c) {
    int idx = (((b * NCHK + c) * 2048) + d) * 16 + s;
    float p  = xz[carve(idx)];
    size_t ha = carve(idx) + (size_t)512 * 4096;
    float hl = xz[ha];
    xz[ha] = h;               // hin for chunk c
    h = fmaf(p, h, hl);
  }
}

__global__ __launch_bounds__(256) void scan_p2(
    const float* __restrict__ A_log, const float* __restrict__ Dvec,
    const float* __restrict__ x_dbl, const float* __restrict__ xc,
    const float* __restrict__ xz, const float* __restrict__ dt,
    unsigned short* __restrict__ ybf)
{
  const int unit = blockIdx.x * 16 + (threadIdx.x >> 4);
  const int s = threadIdx.x & 15;
  const int d = unit & 2047;
  const int c = (unit >> 11) & (NCHK - 1);
  const int b = unit >> 15;
  const float Ac = -expf(A_log[d * 16 + s]);
  const float Dd = Dvec[d];
  const size_t tok0 = (size_t)b * SEQ + c * CH;
  const size_t base = tok0 * 2048 + d;
  const float* xd = x_dbl + tok0 * 96;

  float h = xz[carve(unit * 16 + s) + (size_t)512 * 4096];  // hin
#pragma unroll 2
  for (int l = 0; l < CH; ++l) {
    float dtv = dt[base + (size_t)l * 2048];
    float uv  = xc[base + (size_t)l * 2048];
    float Bs  = xd[l * 96 + 64 + s];
    float Cs  = xd[l * 96 + 80 + s];
    float dA  = expf(dtv * Ac);
    h = fmaf(dA, h, dtv * uv * Bs);
    float pr = h * Cs;
    pr += __shfl_xor(pr, 1, 16);
    pr += __shfl_xor(pr, 2, 16);
    pr += __shfl_xor(pr, 4, 16);
    pr += __shfl_xor(pr, 8, 16);
    if (s == 0) {
      float zv = xz[(tok0 + l) * 4096 + 2048 + d];
      float yv = fmaf(Dd, uv, pr);
      yv *= zv / (1.f + expf(-zv));
      ybf[base + (size_t)l * 2048] = f2bf(yv);
    }
  }
}

// ---------------------------------------------------------------------------
// LayerNorm over 1024, one block (256 thr) per row.
// ---------------------------------------------------------------------------
__global__ __launch_bounds__(256) void ln_k(
    const float* __restrict__ t, const float* __restrict__ g,
    const float* __restrict__ bb, float* __restrict__ out)
{
  int row = blockIdx.x;
  float4 v = ((const float4*)(t + (size_t)row * 1024))[threadIdx.x];
  float s  = v.x + v.y + v.z + v.w;
  float sq = v.x * v.x + v.y * v.y + v.z * v.z + v.w * v.w;
#pragma unroll
  for (int off = 32; off >= 1; off >>= 1) {
    s  += __shfl_xor(s,  off, 64);
    sq += __shfl_xor(sq, off, 64);
  }
  __shared__ float red[8];
  int wid = threadIdx.x >> 6;
  if ((threadIdx.x & 63) == 0) { red[wid] = s; red[4 + wid] = sq; }
  __syncthreads();
  s  = red[0] + red[1] + red[2] + red[3];
  sq = red[4] + red[5] + red[6] + red[7];
  float mu  = s * (1.f / 1024.f);
  float var = sq * (1.f / 1024.f) - mu * mu;
  float r   = rsqrtf(var + 1e-5f);
  int col = threadIdx.x * 4;
  float4 gv = *(const float4*)(g + col);
  float4 bv = *(const float4*)(bb + col);
  float4 o;
  o.x = (v.x - mu) * r * gv.x + bv.x;
  o.y = (v.y - mu) * r * gv.y + bv.y;
  o.z = (v.z - mu) * r * gv.z + bv.z;
  o.w = (v.w - mu) * r * gv.w + bv.w;
  ((float4*)(out + (size_t)row * 1024))[threadIdx.x] = o;
}

// ---------------------------------------------------------------------------
extern "C" void kernel_launch(void* const* d_in, const int* in_sizes, int n_in,
                              void* d_out, int out_size, void* d_ws, size_t ws_size,
                              hipStream_t stream)
{
  const float* x       = (const float*)d_in[0];
  const float* in_proj = (const float*)d_in[1];
  const float* conv_w  = (const float*)d_in[2];
  const float* conv_b  = (const float*)d_in[3];
  const float* x_proj  = (const float*)d_in[4];
  const float* dt_w    = (const float*)d_in[5];
  const float* dt_b    = (const float*)d_in[6];
  const float* A_log   = (const float*)d_in[7];
  const float* Dv      = (const float*)d_in[8];
  const float* out_w   = (const float*)d_in[9];
  const float* ln_g    = (const float*)d_in[10];
  const float* ln_bias = (const float*)d_in[11];
  float* out = (float*)d_out;

  float* ws   = (float*)d_ws;
  float* xz   = ws;                              // NTOK*4096 (xi half -> P/Hl carve)
  float* xc   = xz   + (size_t)NTOK * 4096;      // NTOK*2048 (later: tmp pre-LN)
  float* xdbl = xc   + (size_t)NTOK * 2048;      // NTOK*96
  float* dty  = xdbl + (size_t)NTOK * 96;        // NTOK*2048 dt (x_bf carve at front)
  unsigned short* xc_bf = (unsigned short*)(dty + (size_t)NTOK * 2048); // NTOK*2048
  unsigned short* y_bf  = xc_bf + (size_t)NTOK * 2048;                  // NTOK*2048
  unsigned short* wbuf  = y_bf  + (size_t)NTOK * 2048;                  // 4096*1024
  unsigned short* x_bf  = (unsigned short*)dty;  // carve (dead until dt_proj)
  float* tmp  = xc;                              // pre-LN (xc fp32 dead after scan)

  dim3 blk(256);
  // casts for in_proj
  cast_k<<<dim3(NTOK * 1024 / 1024), blk, 0, stream>>>(x, x_bf, NTOK * 1024);
  cast_k<<<dim3(4096 * 1024 / 1024), blk, 0, stream>>>(in_proj, wbuf, 4096 * 1024);
  // 1) in_proj MFMA: (4096x1024)@(4096x1024)^T -> xz fp32
  mgemm<0><<<dim3(32, 32), blk, 0, stream>>>(x_bf, 1024, wbuf, 1024,
                                             xz, 4096, 4096, 1024, nullptr);
  // 2) conv + silu -> xc fp32 + xc_bf
  conv_silu_k<<<dim3((NTOK * D_INNER) / 256), blk, 0, stream>>>(xz, conv_w, conv_b, xc, xc_bf);
  // 3) x_proj MFMA: -> x_dbl (4096x96) fp32
  cast_k<<<dim3(96 * 2048 / 1024), blk, 0, stream>>>(x_proj, wbuf, 96 * 2048);
  mgemm<0><<<dim3(1, 32), blk, 0, stream>>>(xc_bf, 2048, wbuf, 2048,
                                            xdbl, 96, 96, 2048, nullptr);
  // 4) dt_proj + softplus (fp32, K=64)
  gemm_sp<<<dim3(32, 64), blk, 0, stream>>>(xdbl, 96, dt_w, dty, 2048,
                                            2048, 64, dt_b);
  // 5) chunked selective scan -> y_bf
  scan_p1 <<<dim3(BSZ * NCHK * 2048 / 16), blk, 0, stream>>>(A_log, xdbl, xc, dty, xz);
  scan_fix<<<dim3(BSZ * 2048 * 16 / 256), blk, 0, stream>>>(xz);
  scan_p2 <<<dim3(BSZ * NCHK * 2048 / 16), blk, 0, stream>>>(A_log, Dv, xdbl, xc, xz, dty, y_bf);
  // 6) out_proj MFMA + residual x -> tmp
  cast_k<<<dim3(1024 * 2048 / 1024), blk, 0, stream>>>(out_w, wbuf, 1024 * 2048);
  mgemm<2><<<dim3(8, 32), blk, 0, stream>>>(y_bf, 2048, wbuf, 2048,
                                            tmp, 1024, 1024, 2048, x);
  // 7) layernorm -> out
  ln_k<<<dim3(NTOK), blk, 0, stream>>>(tmp, ln_g, ln_bias, out);
}

// Round 4
// 445.701 us; speedup vs baseline: 5.6234x; 1.4733x over previous
//
#include <hip/hip_runtime.h>
#include <math.h>

#define D_STATE 16
#define D_INNER 2048
#define SEQ     2048
#define BSZ     2
#define NTOK    (BSZ*SEQ)   // 4096
#define CH      32           // scan chunk length
#define NCHK    (SEQ/CH)     // 64 chunks per sequence
#define HLOFF   ((size_t)2048 * 4096)   // Hl region offset inside xz (floats)

typedef __bf16 bf16x8 __attribute__((ext_vector_type(8)));
typedef float  floatx4 __attribute__((ext_vector_type(4)));

__device__ __forceinline__ unsigned short f2bf(float f) {  // RNE fp32->bf16
  unsigned int u = __float_as_uint(f);
  u += 0x7fff + ((u >> 16) & 1);
  return (unsigned short)(u >> 16);
}

__device__ __forceinline__ void gload16(const unsigned short* g, unsigned short* l) {
  __builtin_amdgcn_global_load_lds(
      (const __attribute__((address_space(1))) unsigned int*)g,
      (__attribute__((address_space(3))) unsigned int*)l, 16, 0, 0);
}

// ---------------------------------------------------------------------------
// fp32 -> bf16 cast, 4 elems/thread. n must be divisible by 1024.
// ---------------------------------------------------------------------------
__global__ __launch_bounds__(256) void cast_k(
    const float* __restrict__ src, unsigned short* __restrict__ dst, int n)
{
  int i = (blockIdx.x * 256 + threadIdx.x) * 4;
  if (i < n) {
    float4 v = *(const float4*)(src + i);
    ushort4 o;
    o.x = f2bf(v.x); o.y = f2bf(v.y); o.z = f2bf(v.z); o.w = f2bf(v.w);
    *(ushort4*)(dst + i) = o;
  }
}

// ---------------------------------------------------------------------------
// bf16 MFMA GEMM: C[m,n] = sum_k A[m,k]*W[n,k]  (fp32 accumulate/output)
// 128x128 tile, 256 thr (4 waves), 4x4 16x16x32 frags/wave, BK=32,
// global_load_lds width-16 staging (m97 structure).
// MODE 0: plain   MODE 2: + aux[m*ldc+n] (residual)
// ---------------------------------------------------------------------------
template<int MODE>
__global__ __launch_bounds__(256) void mgemm(
    const unsigned short* __restrict__ A, int lda,
    const unsigned short* __restrict__ W, int ldw,
    float* __restrict__ C, int ldc,
    int N, int K, const float* __restrict__ aux)
{
  __shared__ unsigned short As[128 * 32];
  __shared__ unsigned short Ws[128 * 32];
  const int tid  = threadIdx.x;
  const int wave = tid >> 6, lane = tid & 63;
  const int m0 = blockIdx.y * 128, n0 = blockIdx.x * 128;
  const int srow = lane >> 2, scol = (lane & 3) * 8;
  const int fr = lane & 15, fq = lane >> 4;
  const int wm = (wave >> 1) * 64, wn = (wave & 1) * 64;

  const int ar0 = (wave * 2 + 0) * 16 + srow;
  const int ar1 = (wave * 2 + 1) * 16 + srow;
  int wr0 = n0 + ar0; if (wr0 > N - 1) wr0 = N - 1;
  int wr1 = n0 + ar1; if (wr1 > N - 1) wr1 = N - 1;
  const unsigned short* gA0 = A + (size_t)(m0 + ar0) * lda + scol;
  const unsigned short* gA1 = A + (size_t)(m0 + ar1) * lda + scol;
  const unsigned short* gW0 = W + (size_t)wr0 * ldw + scol;
  const unsigned short* gW1 = W + (size_t)wr1 * ldw + scol;
  unsigned short* lA0 = As + (wave * 2 + 0) * 512;
  unsigned short* lA1 = As + (wave * 2 + 1) * 512;
  unsigned short* lW0 = Ws + (wave * 2 + 0) * 512;
  unsigned short* lW1 = Ws + (wave * 2 + 1) * 512;

  floatx4 zero = {0.f, 0.f, 0.f, 0.f};
  floatx4 acc[4][4];
#pragma unroll
  for (int i = 0; i < 4; ++i)
#pragma unroll
    for (int j = 0; j < 4; ++j) acc[i][j] = zero;

  for (int kt = 0; kt < K; kt += 32) {
    __syncthreads();
    gload16(gA0 + kt, lA0);
    gload16(gA1 + kt, lA1);
    gload16(gW0 + kt, lW0);
    gload16(gW1 + kt, lW1);
    __syncthreads();
    bf16x8 af[4], bfr[4];
#pragma unroll
    for (int i = 0; i < 4; ++i) {
      af[i]  = *(const bf16x8*)(As + (wm + i * 16 + fr) * 32 + fq * 8);
      bfr[i] = *(const bf16x8*)(Ws + (wn + i * 16 + fr) * 32 + fq * 8);
    }
#pragma unroll
    for (int i = 0; i < 4; ++i)
#pragma unroll
      for (int j = 0; j < 4; ++j)
        acc[i][j] = __builtin_amdgcn_mfma_f32_16x16x32_bf16(af[i], bfr[j], acc[i][j], 0, 0, 0);
  }

  // C/D layout: col = lane&15, row = (lane>>4)*4 + reg
#pragma unroll
  for (int i = 0; i < 4; ++i) {
#pragma unroll
    for (int j = 0; j < 4; ++j) {
      int n = n0 + wn + j * 16 + fr;
      if (n < N) {
#pragma unroll
        for (int r = 0; r < 4; ++r) {
          int m = m0 + wm + i * 16 + fq * 4 + r;
          float v = acc[i][j][r];
          if (MODE == 2) v += aux[(size_t)m * ldc + n];
          C[(size_t)m * ldc + n] = v;
        }
      }
    }
  }
}

// ---------------------------------------------------------------------------
// fp32 GEMM (dt_proj, K=64): softplus(acc + aux[n])
// ---------------------------------------------------------------------------
__global__ __launch_bounds__(256) void gemm_sp(
    const float* __restrict__ A, int lda,
    const float* __restrict__ W,
    float* __restrict__ C, int ldc,
    int N, int K, const float* __restrict__ aux)
{
  __shared__ float As[16][68];
  __shared__ float Ws[16][68];
  const int tid = threadIdx.x;
  const int tx = tid & 15, ty = tid >> 4;
  const int m0 = blockIdx.y * 64, n0 = blockIdx.x * 64;
  float acc[4][4] = {};

  for (int kt = 0; kt < K; kt += 16) {
#pragma unroll
    for (int r = 0; r < 4; ++r) {
      int idx = tid + r * 256;
      int mm = idx >> 4, kk = idx & 15;
      As[kk][mm] = A[(size_t)(m0 + mm) * lda + kt + kk];
      float wv = 0.f;
      if (n0 + mm < N) wv = W[(size_t)(n0 + mm) * K + kt + kk];
      Ws[kk][mm] = wv;
    }
    __syncthreads();
#pragma unroll
    for (int kk = 0; kk < 16; ++kk) {
      float4 a = *(const float4*)&As[kk][ty * 4];
      float4 b = *(const float4*)&Ws[kk][tx * 4];
      float av[4] = {a.x, a.y, a.z, a.w};
      float bv[4] = {b.x, b.y, b.z, b.w};
#pragma unroll
      for (int i = 0; i < 4; ++i)
#pragma unroll
        for (int j = 0; j < 4; ++j)
          acc[i][j] = fmaf(av[i], bv[j], acc[i][j]);
    }
    __syncthreads();
  }

#pragma unroll
  for (int i = 0; i < 4; ++i) {
    int m = m0 + ty * 4 + i;
#pragma unroll
    for (int j = 0; j < 4; ++j) {
      int n = n0 + tx * 4 + j;
      if (n < N) {
        float v = acc[i][j] + aux[n];
        v = (v > 20.f) ? v : log1pf(__expf(v));
        C[(size_t)m * ldc + n] = v;
      }
    }
  }
}

// ---------------------------------------------------------------------------
// Depthwise causal conv(4) + bias + SiLU. Writes fp32 xc and bf16 xc_bf.
// ---------------------------------------------------------------------------
__global__ __launch_bounds__(256) void conv_silu_k(
    const float* __restrict__ xz, const float* __restrict__ w,
    const float* __restrict__ b, float* __restrict__ xc,
    unsigned short* __restrict__ xcb)
{
  int idx = blockIdx.x * 256 + threadIdx.x;   // over NTOK*D_INNER
  int e  = idx & (D_INNER - 1);
  int bl = idx >> 11;                          // b*SEQ + l
  int l  = bl & (SEQ - 1);
  float acc = b[e];
#pragma unroll
  for (int k = 0; k < 4; ++k) {
    int ll = l - 3 + k;
    if (ll >= 0)
      acc = fmaf(xz[(size_t)(bl + ll - l) * 4096 + e], w[e * 4 + k], acc);
  }
  float v = acc / (1.f + __expf(-acc));        // silu
  xc[idx] = v;
  xcb[idx] = f2bf(v);
}

// ---------------------------------------------------------------------------
// Chunked selective scan, all 16 states per thread.
// thread t = (b*NCHK + c)*2048 + d.  P/Hl carved into dead xi half of xz:
//   flat idx = t*16+s -> row (idx>>11), col (idx&2047); Hl at +HLOFF.
// ---------------------------------------------------------------------------
__global__ __launch_bounds__(256) void scan_p1(
    const float* __restrict__ A_log,
    const float* __restrict__ x_dbl, const float* __restrict__ xc,
    const float* __restrict__ dt, float* __restrict__ xz)
{
  const int t = blockIdx.x * 256 + threadIdx.x;
  const int d = t & 2047;
  const int c = (t >> 11) & (NCHK - 1);
  const int b = t >> 17;
  const size_t tok0 = (size_t)b * SEQ + c * CH;
  const float* xd = x_dbl + tok0 * 96;

  float Ac[16];
  {
    float4 a0 = *(const float4*)(A_log + d * 16);
    float4 a1 = *(const float4*)(A_log + d * 16 + 4);
    float4 a2 = *(const float4*)(A_log + d * 16 + 8);
    float4 a3 = *(const float4*)(A_log + d * 16 + 12);
    Ac[0]=-__expf(a0.x); Ac[1]=-__expf(a0.y); Ac[2]=-__expf(a0.z); Ac[3]=-__expf(a0.w);
    Ac[4]=-__expf(a1.x); Ac[5]=-__expf(a1.y); Ac[6]=-__expf(a1.z); Ac[7]=-__expf(a1.w);
    Ac[8]=-__expf(a2.x); Ac[9]=-__expf(a2.y); Ac[10]=-__expf(a2.z); Ac[11]=-__expf(a2.w);
    Ac[12]=-__expf(a3.x); Ac[13]=-__expf(a3.y); Ac[14]=-__expf(a3.z); Ac[15]=-__expf(a3.w);
  }

  float p[16], h[16];
#pragma unroll
  for (int s = 0; s < 16; ++s) { p[s] = 1.f; h[s] = 0.f; }

  for (int l = 0; l < CH; ++l) {
    float dtv = dt[(tok0 + l) * 2048 + d];
    float uv  = xc[(tok0 + l) * 2048 + d];
    float du  = dtv * uv;
    float Bv[16];
#pragma unroll
    for (int j = 0; j < 4; ++j) {
      float4 bb = *(const float4*)(xd + l * 96 + 64 + j * 4);
      Bv[j*4+0]=bb.x; Bv[j*4+1]=bb.y; Bv[j*4+2]=bb.z; Bv[j*4+3]=bb.w;
    }
#pragma unroll
    for (int s = 0; s < 16; ++s) {
      float dA = __expf(dtv * Ac[s]);
      p[s] *= dA;
      h[s] = fmaf(dA, h[s], du * Bv[s]);
    }
  }

  float* pp = xz + ((size_t)(t >> 7)) * 4096 + ((t << 4) & 2047);
#pragma unroll
  for (int j = 0; j < 4; ++j) {
    *(float4*)(pp + j * 4)         = make_float4(p[j*4], p[j*4+1], p[j*4+2], p[j*4+3]);
    *(float4*)(pp + HLOFF + j * 4) = make_float4(h[j*4], h[j*4+1], h[j*4+2], h[j*4+3]);
  }
}

// Sequential fix-up over chunks: overwrite Hl[c] with chunk-entry state hin[c].
__global__ __launch_bounds__(256) void scan_fix(float* __restrict__ xz)
{
  int tid = blockIdx.x * 256 + threadIdx.x;  // (b*2048+d)*16+s
  int s = tid & 15;
  int d = (tid >> 4) & 2047;
  int b = tid >> 15;
  float h = 0.f;
  for (int c = 0; c < NCHK; ++c) {
    size_t idx = ((((size_t)(b * NCHK + c) * 2048) + d) * 16) + s;
    size_t addr = (idx >> 11) * 4096 + (idx & 2047);
    float p  = xz[addr];
    float hl = xz[addr + HLOFF];
    xz[addr + HLOFF] = h;               // hin for chunk c
    h = fmaf(p, h, hl);
  }
}

__global__ __launch_bounds__(256) void scan_p2(
    const float* __restrict__ A_log, const float* __restrict__ Dvec,
    const float* __restrict__ x_dbl, const float* __restrict__ xc,
    const float* __restrict__ xz, const float* __restrict__ dt,
    unsigned short* __restrict__ ybf)
{
  const int t = blockIdx.x * 256 + threadIdx.x;
  const int d = t & 2047;
  const int c = (t >> 11) & (NCHK - 1);
  const int b = t >> 17;
  const size_t tok0 = (size_t)b * SEQ + c * CH;
  const float* xd = x_dbl + tok0 * 96;
  const float Dd = Dvec[d];

  float Ac[16];
  {
    float4 a0 = *(const float4*)(A_log + d * 16);
    float4 a1 = *(const float4*)(A_log + d * 16 + 4);
    float4 a2 = *(const float4*)(A_log + d * 16 + 8);
    float4 a3 = *(const float4*)(A_log + d * 16 + 12);
    Ac[0]=-__expf(a0.x); Ac[1]=-__expf(a0.y); Ac[2]=-__expf(a0.z); Ac[3]=-__expf(a0.w);
    Ac[4]=-__expf(a1.x); Ac[5]=-__expf(a1.y); Ac[6]=-__expf(a1.z); Ac[7]=-__expf(a1.w);
    Ac[8]=-__expf(a2.x); Ac[9]=-__expf(a2.y); Ac[10]=-__expf(a2.z); Ac[11]=-__expf(a2.w);
    Ac[12]=-__expf(a3.x); Ac[13]=-__expf(a3.y); Ac[14]=-__expf(a3.z); Ac[15]=-__expf(a3.w);
  }

  const float* pp = xz + ((size_t)(t >> 7)) * 4096 + ((t << 4) & 2047);
  float h[16];
#pragma unroll
  for (int j = 0; j < 4; ++j) {
    float4 hh = *(const float4*)(pp + HLOFF + j * 4);
    h[j*4+0]=hh.x; h[j*4+1]=hh.y; h[j*4+2]=hh.z; h[j*4+3]=hh.w;
  }

  for (int l = 0; l < CH; ++l) {
    float dtv = dt[(tok0 + l) * 2048 + d];
    float uv  = xc[(tok0 + l) * 2048 + d];
    float zv  = xz[(tok0 + l) * 4096 + 2048 + d];
    float du  = dtv * uv;
    float Bv[16], Cv[16];
#pragma unroll
    for (int j = 0; j < 4; ++j) {
      float4 bb = *(const float4*)(xd + l * 96 + 64 + j * 4);
      float4 cc = *(const float4*)(xd + l * 96 + 80 + j * 4);
      Bv[j*4+0]=bb.x; Bv[j*4+1]=bb.y; Bv[j*4+2]=bb.z; Bv[j*4+3]=bb.w;
      Cv[j*4+0]=cc.x; Cv[j*4+1]=cc.y; Cv[j*4+2]=cc.z; Cv[j*4+3]=cc.w;
    }
    float y = 0.f;
#pragma unroll
    for (int s = 0; s < 16; ++s) {
      float dA = __expf(dtv * Ac[s]);
      h[s] = fmaf(dA, h[s], du * Bv[s]);
      y = fmaf(h[s], Cv[s], y);
    }
    y = fmaf(Dd, uv, y);
    y *= zv / (1.f + __expf(-zv));
    ybf[(tok0 + l) * 2048 + d] = f2bf(y);
  }
}

// ---------------------------------------------------------------------------
// LayerNorm over 1024, one block (256 thr) per row.
// ---------------------------------------------------------------------------
__global__ __launch_bounds__(256) void ln_k(
    const float* __restrict__ t, const float* __restrict__ g,
    const float* __restrict__ bb, float* __restrict__ out)
{
  int row = blockIdx.x;
  float4 v = ((const float4*)(t + (size_t)row * 1024))[threadIdx.x];
  float s  = v.x + v.y + v.z + v.w;
  float sq = v.x * v.x + v.y * v.y + v.z * v.z + v.w * v.w;
#pragma unroll
  for (int off = 32; off >= 1; off >>= 1) {
    s  += __shfl_xor(s,  off, 64);
    sq += __shfl_xor(sq, off, 64);
  }
  __shared__ float red[8];
  int wid = threadIdx.x >> 6;
  if ((threadIdx.x & 63) == 0) { red[wid] = s; red[4 + wid] = sq; }
  __syncthreads();
  s  = red[0] + red[1] + red[2] + red[3];
  sq = red[4] + red[5] + red[6] + red[7];
  float mu  = s * (1.f / 1024.f);
  float var = sq * (1.f / 1024.f) - mu * mu;
  float r   = rsqrtf(var + 1e-5f);
  int col = threadIdx.x * 4;
  float4 gv = *(const float4*)(g + col);
  float4 bv = *(const float4*)(bb + col);
  float4 o;
  o.x = (v.x - mu) * r * gv.x + bv.x;
  o.y = (v.y - mu) * r * gv.y + bv.y;
  o.z = (v.z - mu) * r * gv.z + bv.z;
  o.w = (v.w - mu) * r * gv.w + bv.w;
  ((float4*)(out + (size_t)row * 1024))[threadIdx.x] = o;
}

// ---------------------------------------------------------------------------
extern "C" void kernel_launch(void* const* d_in, const int* in_sizes, int n_in,
                              void* d_out, int out_size, void* d_ws, size_t ws_size,
                              hipStream_t stream)
{
  const float* x       = (const float*)d_in[0];
  const float* in_proj = (const float*)d_in[1];
  const float* conv_w  = (const float*)d_in[2];
  const float* conv_b  = (const float*)d_in[3];
  const float* x_proj  = (const float*)d_in[4];
  const float* dt_w    = (const float*)d_in[5];
  const float* dt_b    = (const float*)d_in[6];
  const float* A_log   = (const float*)d_in[7];
  const float* Dv      = (const float*)d_in[8];
  const float* out_w   = (const float*)d_in[9];
  const float* ln_g    = (const float*)d_in[10];
  const float* ln_bias = (const float*)d_in[11];
  float* out = (float*)d_out;

  float* ws   = (float*)d_ws;
  float* xz   = ws;                              // NTOK*4096 (xi half -> P/Hl carve)
  float* xc   = xz   + (size_t)NTOK * 4096;      // NTOK*2048 (later: tmp pre-LN)
  float* xdbl = xc   + (size_t)NTOK * 2048;      // NTOK*96
  float* dty  = xdbl + (size_t)NTOK * 96;        // NTOK*2048 dt (x_bf carve at front)
  unsigned short* xc_bf = (unsigned short*)(dty + (size_t)NTOK * 2048); // NTOK*2048
  unsigned short* y_bf  = xc_bf + (size_t)NTOK * 2048;                  // NTOK*2048
  unsigned short* wbuf  = y_bf  + (size_t)NTOK * 2048;                  // 4096*1024
  unsigned short* x_bf  = (unsigned short*)dty;  // carve (dead until dt_proj)
  float* tmp  = xc;                              // pre-LN (xc fp32 dead after scan)

  dim3 blk(256);
  // casts for in_proj
  cast_k<<<dim3(NTOK * 1024 / 1024), blk, 0, stream>>>(x, x_bf, NTOK * 1024);
  cast_k<<<dim3(4096 * 1024 / 1024), blk, 0, stream>>>(in_proj, wbuf, 4096 * 1024);
  // 1) in_proj MFMA: (4096x1024)@(4096x1024)^T -> xz fp32
  mgemm<0><<<dim3(32, 32), blk, 0, stream>>>(x_bf, 1024, wbuf, 1024,
                                             xz, 4096, 4096, 1024, nullptr);
  // 2) conv + silu -> xc fp32 + xc_bf
  conv_silu_k<<<dim3((NTOK * D_INNER) / 256), blk, 0, stream>>>(xz, conv_w, conv_b, xc, xc_bf);
  // 3) x_proj MFMA: -> x_dbl (4096x96) fp32
  cast_k<<<dim3(96 * 2048 / 1024), blk, 0, stream>>>(x_proj, wbuf, 96 * 2048);
  mgemm<0><<<dim3(1, 32), blk, 0, stream>>>(xc_bf, 2048, wbuf, 2048,
                                            xdbl, 96, 96, 2048, nullptr);
  // 4) dt_proj + softplus (fp32, K=64)
  gemm_sp<<<dim3(32, 64), blk, 0, stream>>>(xdbl, 96, dt_w, dty, 2048,
                                            2048, 64, dt_b);
  // 5) chunked selective scan -> y_bf
  scan_p1 <<<dim3(BSZ * NCHK * 2048 / 256), blk, 0, stream>>>(A_log, xdbl, xc, dty, xz);
  scan_fix<<<dim3(BSZ * 2048 * 16 / 256), blk, 0, stream>>>(xz);
  scan_p2 <<<dim3(BSZ * NCHK * 2048 / 256), blk, 0, stream>>>(A_log, Dv, xdbl, xc, xz, dty, y_bf);
  // 6) out_proj MFMA + residual x -> tmp
  cast_k<<<dim3(1024 * 2048 / 1024), blk, 0, stream>>>(out_w, wbuf, 1024 * 2048);
  mgemm<2><<<dim3(8, 32), blk, 0, stream>>>(y_bf, 2048, wbuf, 2048,
                                            tmp, 1024, 1024, 2048, x);
  // 7) layernorm -> out
  ln_k<<<dim3(NTOK), blk, 0, stream>>>(tmp, ln_g, ln_bias, out);
}

// Round 5
// 434.150 us; speedup vs baseline: 5.7730x; 1.0266x over previous
//
#include <hip/hip_runtime.h>
#include <math.h>

#define D_STATE 16
#define D_INNER 2048
#define SEQ     2048
#define BSZ     2
#define NTOK    (BSZ*SEQ)   // 4096
#define CH      32           // scan chunk length
#define NCHK    (SEQ/CH)     // 64 chunks per sequence
#define HLOFF   ((size_t)2048 * 4096)   // Hl region offset inside xz (floats)

typedef __bf16 bf16x8 __attribute__((ext_vector_type(8)));
typedef float  floatx4 __attribute__((ext_vector_type(4)));

__device__ __forceinline__ unsigned short f2bf(float f) {  // RNE fp32->bf16
  unsigned int u = __float_as_uint(f);
  u += 0x7fff + ((u >> 16) & 1);
  return (unsigned short)(u >> 16);
}

__device__ __forceinline__ void gload16(const unsigned short* g, unsigned short* l) {
  __builtin_amdgcn_global_load_lds(
      (const __attribute__((address_space(1))) unsigned int*)g,
      (__attribute__((address_space(3))) unsigned int*)l, 16, 0, 0);
}

// ---------------------------------------------------------------------------
// fp32 -> bf16 cast, 4 elems/thread. n must be divisible by 1024.
// ---------------------------------------------------------------------------
__global__ __launch_bounds__(256) void cast_k(
    const float* __restrict__ src, unsigned short* __restrict__ dst, int n)
{
  int i = (blockIdx.x * 256 + threadIdx.x) * 4;
  if (i < n) {
    float4 v = *(const float4*)(src + i);
    ushort4 o;
    o.x = f2bf(v.x); o.y = f2bf(v.y); o.z = f2bf(v.z); o.w = f2bf(v.w);
    *(ushort4*)(dst + i) = o;
  }
}

// Strided cast: dt_r (cols 0..63 of x_dbl rows of 96) -> bf16, dst stride 64.
__global__ __launch_bounds__(256) void cast_dtr(
    const float* __restrict__ src, unsigned short* __restrict__ dst)
{
  int i = (blockIdx.x * 256 + threadIdx.x) * 4;   // over 4096*64
  int m = i >> 6, col = i & 63;
  float4 v = *(const float4*)(src + (size_t)m * 96 + col);
  ushort4 o;
  o.x = f2bf(v.x); o.y = f2bf(v.y); o.z = f2bf(v.z); o.w = f2bf(v.w);
  *(ushort4*)(dst + (size_t)m * 64 + col) = o;
}

// ---------------------------------------------------------------------------
// bf16 MFMA GEMM: C[m,n] = sum_k A[m,k]*W[n,k]  (fp32 accumulate/output)
// 128x128 tile, 256 thr (4 waves), 4x4 16x16x32 frags/wave, BK=32,
// global_load_lds width-16 staging (m97 structure).
// MODE 0: plain   MODE 1: softplus(acc + aux[n])   MODE 2: + aux[m*ldc+n]
// ---------------------------------------------------------------------------
template<int MODE>
__global__ __launch_bounds__(256) void mgemm(
    const unsigned short* __restrict__ A, int lda,
    const unsigned short* __restrict__ W, int ldw,
    float* __restrict__ C, int ldc,
    int N, int K, const float* __restrict__ aux)
{
  __shared__ unsigned short As[128 * 32];
  __shared__ unsigned short Ws[128 * 32];
  const int tid  = threadIdx.x;
  const int wave = tid >> 6, lane = tid & 63;
  const int m0 = blockIdx.y * 128, n0 = blockIdx.x * 128;
  const int srow = lane >> 2, scol = (lane & 3) * 8;
  const int fr = lane & 15, fq = lane >> 4;
  const int wm = (wave >> 1) * 64, wn = (wave & 1) * 64;

  const int ar0 = (wave * 2 + 0) * 16 + srow;
  const int ar1 = (wave * 2 + 1) * 16 + srow;
  int wr0 = n0 + ar0; if (wr0 > N - 1) wr0 = N - 1;
  int wr1 = n0 + ar1; if (wr1 > N - 1) wr1 = N - 1;
  const unsigned short* gA0 = A + (size_t)(m0 + ar0) * lda + scol;
  const unsigned short* gA1 = A + (size_t)(m0 + ar1) * lda + scol;
  const unsigned short* gW0 = W + (size_t)wr0 * ldw + scol;
  const unsigned short* gW1 = W + (size_t)wr1 * ldw + scol;
  unsigned short* lA0 = As + (wave * 2 + 0) * 512;
  unsigned short* lA1 = As + (wave * 2 + 1) * 512;
  unsigned short* lW0 = Ws + (wave * 2 + 0) * 512;
  unsigned short* lW1 = Ws + (wave * 2 + 1) * 512;

  floatx4 zero = {0.f, 0.f, 0.f, 0.f};
  floatx4 acc[4][4];
#pragma unroll
  for (int i = 0; i < 4; ++i)
#pragma unroll
    for (int j = 0; j < 4; ++j) acc[i][j] = zero;

  for (int kt = 0; kt < K; kt += 32) {
    __syncthreads();
    gload16(gA0 + kt, lA0);
    gload16(gA1 + kt, lA1);
    gload16(gW0 + kt, lW0);
    gload16(gW1 + kt, lW1);
    __syncthreads();
    bf16x8 af[4], bfr[4];
#pragma unroll
    for (int i = 0; i < 4; ++i) {
      af[i]  = *(const bf16x8*)(As + (wm + i * 16 + fr) * 32 + fq * 8);
      bfr[i] = *(const bf16x8*)(Ws + (wn + i * 16 + fr) * 32 + fq * 8);
    }
#pragma unroll
    for (int i = 0; i < 4; ++i)
#pragma unroll
      for (int j = 0; j < 4; ++j)
        acc[i][j] = __builtin_amdgcn_mfma_f32_16x16x32_bf16(af[i], bfr[j], acc[i][j], 0, 0, 0);
  }

  // C/D layout: col = lane&15, row = (lane>>4)*4 + reg
#pragma unroll
  for (int i = 0; i < 4; ++i) {
#pragma unroll
    for (int j = 0; j < 4; ++j) {
      int n = n0 + wn + j * 16 + fr;
      if (n < N) {
#pragma unroll
        for (int r = 0; r < 4; ++r) {
          int m = m0 + wm + i * 16 + fq * 4 + r;
          float v = acc[i][j][r];
          if (MODE == 1) { v += aux[n]; v = (v > 20.f) ? v : log1pf(__expf(v)); }
          if (MODE == 2) v += aux[(size_t)m * ldc + n];
          C[(size_t)m * ldc + n] = v;
        }
      }
    }
  }
}

// ---------------------------------------------------------------------------
// Depthwise causal conv(4) + bias + SiLU. Writes fp32 xc and bf16 xc_bf.
// ---------------------------------------------------------------------------
__global__ __launch_bounds__(256) void conv_silu_k(
    const float* __restrict__ xz, const float* __restrict__ w,
    const float* __restrict__ b, float* __restrict__ xc,
    unsigned short* __restrict__ xcb)
{
  int idx = blockIdx.x * 256 + threadIdx.x;   // over NTOK*D_INNER
  int e  = idx & (D_INNER - 1);
  int bl = idx >> 11;                          // b*SEQ + l
  int l  = bl & (SEQ - 1);
  float acc = b[e];
#pragma unroll
  for (int k = 0; k < 4; ++k) {
    int ll = l - 3 + k;
    if (ll >= 0)
      acc = fmaf(xz[(size_t)(bl + ll - l) * 4096 + e], w[e * 4 + k], acc);
  }
  float v = acc / (1.f + __expf(-acc));        // silu
  xc[idx] = v;
  xcb[idx] = f2bf(v);
}

// ---------------------------------------------------------------------------
// Chunked selective scan, all 16 states per thread.
// thread t = (b*NCHK + c)*2048 + d.  P/Hl carved into dead xi half of xz:
//   flat idx = t*16+s -> row (idx>>11), col (idx&2047); Hl at +HLOFF.
// ---------------------------------------------------------------------------
__global__ __launch_bounds__(256) void scan_p1(
    const float* __restrict__ A_log,
    const float* __restrict__ x_dbl, const float* __restrict__ xc,
    const float* __restrict__ dt, float* __restrict__ xz)
{
  const int t = blockIdx.x * 256 + threadIdx.x;
  const int d = t & 2047;
  const int c = (t >> 11) & (NCHK - 1);
  const int b = t >> 17;
  const size_t tok0 = (size_t)b * SEQ + c * CH;
  const float* xd = x_dbl + tok0 * 96;

  float Ac[16];
  {
    float4 a0 = *(const float4*)(A_log + d * 16);
    float4 a1 = *(const float4*)(A_log + d * 16 + 4);
    float4 a2 = *(const float4*)(A_log + d * 16 + 8);
    float4 a3 = *(const float4*)(A_log + d * 16 + 12);
    Ac[0]=-__expf(a0.x); Ac[1]=-__expf(a0.y); Ac[2]=-__expf(a0.z); Ac[3]=-__expf(a0.w);
    Ac[4]=-__expf(a1.x); Ac[5]=-__expf(a1.y); Ac[6]=-__expf(a1.z); Ac[7]=-__expf(a1.w);
    Ac[8]=-__expf(a2.x); Ac[9]=-__expf(a2.y); Ac[10]=-__expf(a2.z); Ac[11]=-__expf(a2.w);
    Ac[12]=-__expf(a3.x); Ac[13]=-__expf(a3.y); Ac[14]=-__expf(a3.z); Ac[15]=-__expf(a3.w);
  }

  float p[16], h[16];
#pragma unroll
  for (int s = 0; s < 16; ++s) { p[s] = 1.f; h[s] = 0.f; }

  for (int l = 0; l < CH; ++l) {
    float dtv = dt[(tok0 + l) * 2048 + d];
    float uv  = xc[(tok0 + l) * 2048 + d];
    float du  = dtv * uv;
    float Bv[16];
#pragma unroll
    for (int j = 0; j < 4; ++j) {
      float4 bb = *(const float4*)(xd + l * 96 + 64 + j * 4);
      Bv[j*4+0]=bb.x; Bv[j*4+1]=bb.y; Bv[j*4+2]=bb.z; Bv[j*4+3]=bb.w;
    }
#pragma unroll
    for (int s = 0; s < 16; ++s) {
      float dA = __expf(dtv * Ac[s]);
      p[s] *= dA;
      h[s] = fmaf(dA, h[s], du * Bv[s]);
    }
  }

  float* pp = xz + ((size_t)(t >> 7)) * 4096 + ((t << 4) & 2047);
#pragma unroll
  for (int j = 0; j < 4; ++j) {
    *(float4*)(pp + j * 4)         = make_float4(p[j*4], p[j*4+1], p[j*4+2], p[j*4+3]);
    *(float4*)(pp + HLOFF + j * 4) = make_float4(h[j*4], h[j*4+1], h[j*4+2], h[j*4+3]);
  }
}

// Sequential fix-up over chunks: overwrite Hl[c] with chunk-entry state hin[c].
__global__ __launch_bounds__(256) void scan_fix(float* __restrict__ xz)
{
  int tid = blockIdx.x * 256 + threadIdx.x;  // (b*2048+d)*16+s
  int s = tid & 15;
  int d = (tid >> 4) & 2047;
  int b = tid >> 15;
  float h = 0.f;
  for (int c = 0; c < NCHK; ++c) {
    size_t idx = ((((size_t)(b * NCHK + c) * 2048) + d) * 16) + s;
    size_t addr = (idx >> 11) * 4096 + (idx & 2047);
    float p  = xz[addr];
    float hl = xz[addr + HLOFF];
    xz[addr + HLOFF] = h;               // hin for chunk c
    h = fmaf(p, h, hl);
  }
}

__global__ __launch_bounds__(256) void scan_p2(
    const float* __restrict__ A_log, const float* __restrict__ Dvec,
    const float* __restrict__ x_dbl, const float* __restrict__ xc,
    const float* __restrict__ xz, const float* __restrict__ dt,
    unsigned short* __restrict__ ybf)
{
  const int t = blockIdx.x * 256 + threadIdx.x;
  const int d = t & 2047;
  const int c = (t >> 11) & (NCHK - 1);
  const int b = t >> 17;
  const size_t tok0 = (size_t)b * SEQ + c * CH;
  const float* xd = x_dbl + tok0 * 96;
  const float Dd = Dvec[d];

  float Ac[16];
  {
    float4 a0 = *(const float4*)(A_log + d * 16);
    float4 a1 = *(const float4*)(A_log + d * 16 + 4);
    float4 a2 = *(const float4*)(A_log + d * 16 + 8);
    float4 a3 = *(const float4*)(A_log + d * 16 + 12);
    Ac[0]=-__expf(a0.x); Ac[1]=-__expf(a0.y); Ac[2]=-__expf(a0.z); Ac[3]=-__expf(a0.w);
    Ac[4]=-__expf(a1.x); Ac[5]=-__expf(a1.y); Ac[6]=-__expf(a1.z); Ac[7]=-__expf(a1.w);
    Ac[8]=-__expf(a2.x); Ac[9]=-__expf(a2.y); Ac[10]=-__expf(a2.z); Ac[11]=-__expf(a2.w);
    Ac[12]=-__expf(a3.x); Ac[13]=-__expf(a3.y); Ac[14]=-__expf(a3.z); Ac[15]=-__expf(a3.w);
  }

  const float* pp = xz + ((size_t)(t >> 7)) * 4096 + ((t << 4) & 2047);
  float h[16];
#pragma unroll
  for (int j = 0; j < 4; ++j) {
    float4 hh = *(const float4*)(pp + HLOFF + j * 4);
    h[j*4+0]=hh.x; h[j*4+1]=hh.y; h[j*4+2]=hh.z; h[j*4+3]=hh.w;
  }

  for (int l = 0; l < CH; ++l) {
    float dtv = dt[(tok0 + l) * 2048 + d];
    float uv  = xc[(tok0 + l) * 2048 + d];
    float zv  = xz[(tok0 + l) * 4096 + 2048 + d];
    float du  = dtv * uv;
    float Bv[16], Cv[16];
#pragma unroll
    for (int j = 0; j < 4; ++j) {
      float4 bb = *(const float4*)(xd + l * 96 + 64 + j * 4);
      float4 cc = *(const float4*)(xd + l * 96 + 80 + j * 4);
      Bv[j*4+0]=bb.x; Bv[j*4+1]=bb.y; Bv[j*4+2]=bb.z; Bv[j*4+3]=bb.w;
      Cv[j*4+0]=cc.x; Cv[j*4+1]=cc.y; Cv[j*4+2]=cc.z; Cv[j*4+3]=cc.w;
    }
    float y = 0.f;
#pragma unroll
    for (int s = 0; s < 16; ++s) {
      float dA = __expf(dtv * Ac[s]);
      h[s] = fmaf(dA, h[s], du * Bv[s]);
      y = fmaf(h[s], Cv[s], y);
    }
    y = fmaf(Dd, uv, y);
    y *= zv / (1.f + __expf(-zv));
    ybf[(tok0 + l) * 2048 + d] = f2bf(y);
  }
}

// ---------------------------------------------------------------------------
// LayerNorm over 1024, one block (256 thr) per row.
// ---------------------------------------------------------------------------
__global__ __launch_bounds__(256) void ln_k(
    const float* __restrict__ t, const float* __restrict__ g,
    const float* __restrict__ bb, float* __restrict__ out)
{
  int row = blockIdx.x;
  float4 v = ((const float4*)(t + (size_t)row * 1024))[threadIdx.x];
  float s  = v.x + v.y + v.z + v.w;
  float sq = v.x * v.x + v.y * v.y + v.z * v.z + v.w * v.w;
#pragma unroll
  for (int off = 32; off >= 1; off >>= 1) {
    s  += __shfl_xor(s,  off, 64);
    sq += __shfl_xor(sq, off, 64);
  }
  __shared__ float red[8];
  int wid = threadIdx.x >> 6;
  if ((threadIdx.x & 63) == 0) { red[wid] = s; red[4 + wid] = sq; }
  __syncthreads();
  s  = red[0] + red[1] + red[2] + red[3];
  sq = red[4] + red[5] + red[6] + red[7];
  float mu  = s * (1.f / 1024.f);
  float var = sq * (1.f / 1024.f) - mu * mu;
  float r   = rsqrtf(var + 1e-5f);
  int col = threadIdx.x * 4;
  float4 gv = *(const float4*)(g + col);
  float4 bv = *(const float4*)(bb + col);
  float4 o;
  o.x = (v.x - mu) * r * gv.x + bv.x;
  o.y = (v.y - mu) * r * gv.y + bv.y;
  o.z = (v.z - mu) * r * gv.z + bv.z;
  o.w = (v.w - mu) * r * gv.w + bv.w;
  ((float4*)(out + (size_t)row * 1024))[threadIdx.x] = o;
}

// ---------------------------------------------------------------------------
extern "C" void kernel_launch(void* const* d_in, const int* in_sizes, int n_in,
                              void* d_out, int out_size, void* d_ws, size_t ws_size,
                              hipStream_t stream)
{
  const float* x       = (const float*)d_in[0];
  const float* in_proj = (const float*)d_in[1];
  const float* conv_w  = (const float*)d_in[2];
  const float* conv_b  = (const float*)d_in[3];
  const float* x_proj  = (const float*)d_in[4];
  const float* dt_w    = (const float*)d_in[5];
  const float* dt_b    = (const float*)d_in[6];
  const float* A_log   = (const float*)d_in[7];
  const float* Dv      = (const float*)d_in[8];
  const float* out_w   = (const float*)d_in[9];
  const float* ln_g    = (const float*)d_in[10];
  const float* ln_bias = (const float*)d_in[11];
  float* out = (float*)d_out;

  float* ws   = (float*)d_ws;
  float* xz   = ws;                              // NTOK*4096 (xi half -> P/Hl carve)
  float* xc   = xz   + (size_t)NTOK * 4096;      // NTOK*2048 (later: tmp pre-LN)
  float* xdbl = xc   + (size_t)NTOK * 2048;      // NTOK*96
  float* dty  = xdbl + (size_t)NTOK * 96;        // NTOK*2048 dt (x_bf carve at front)
  unsigned short* xc_bf = (unsigned short*)(dty + (size_t)NTOK * 2048); // NTOK*2048
  unsigned short* y_bf  = xc_bf + (size_t)NTOK * 2048;                  // NTOK*2048
  unsigned short* wbuf  = y_bf  + (size_t)NTOK * 2048;                  // 4096*1024
  unsigned short* x_bf  = (unsigned short*)dty;  // carve (dead until dt_proj)
  unsigned short* dtr_bf = xc_bf;                // reuse (dead after x_proj mgemm)
  float* tmp  = xc;                              // pre-LN (xc fp32 dead after scan)

  dim3 blk(256);
  // casts for in_proj
  cast_k<<<dim3(NTOK * 1024 / 1024), blk, 0, stream>>>(x, x_bf, NTOK * 1024);
  cast_k<<<dim3(4096 * 1024 / 1024), blk, 0, stream>>>(in_proj, wbuf, 4096 * 1024);
  // 1) in_proj MFMA: (4096x1024)@(4096x1024)^T -> xz fp32
  mgemm<0><<<dim3(32, 32), blk, 0, stream>>>(x_bf, 1024, wbuf, 1024,
                                             xz, 4096, 4096, 1024, nullptr);
  // 2) conv + silu -> xc fp32 + xc_bf
  conv_silu_k<<<dim3((NTOK * D_INNER) / 256), blk, 0, stream>>>(xz, conv_w, conv_b, xc, xc_bf);
  // 3) x_proj MFMA: -> x_dbl (4096x96) fp32
  cast_k<<<dim3(96 * 2048 / 1024), blk, 0, stream>>>(x_proj, wbuf, 96 * 2048);
  mgemm<0><<<dim3(1, 32), blk, 0, stream>>>(xc_bf, 2048, wbuf, 2048,
                                            xdbl, 96, 96, 2048, nullptr);
  // 4) dt_proj + softplus via MFMA (K=64); dtr/dt_w cast to bf16 first.
  //    dtr_bf reuses xc_bf (dead after x_proj); dt_w bf16 reuses wbuf.
  cast_dtr<<<dim3(NTOK * 64 / 1024), blk, 0, stream>>>(xdbl, dtr_bf);
  cast_k<<<dim3(2048 * 64 / 1024), blk, 0, stream>>>(dt_w, wbuf, 2048 * 64);
  mgemm<1><<<dim3(16, 32), blk, 0, stream>>>(dtr_bf, 64, wbuf, 64,
                                             dty, 2048, 2048, 64, dt_b);
  // 5) chunked selective scan -> y_bf
  scan_p1 <<<dim3(BSZ * NCHK * 2048 / 256), blk, 0, stream>>>(A_log, xdbl, xc, dty, xz);
  scan_fix<<<dim3(BSZ * 2048 * 16 / 256), blk, 0, stream>>>(xz);
  scan_p2 <<<dim3(BSZ * NCHK * 2048 / 256), blk, 0, stream>>>(A_log, Dv, xdbl, xc, xz, dty, y_bf);
  // 6) out_proj MFMA + residual x -> tmp
  cast_k<<<dim3(1024 * 2048 / 1024), blk, 0, stream>>>(out_w, wbuf, 1024 * 2048);
  mgemm<2><<<dim3(8, 32), blk, 0, stream>>>(y_bf, 2048, wbuf, 2048,
                                            tmp, 1024, 1024, 2048, x);
  // 7) layernorm -> out
  ln_k<<<dim3(NTOK), blk, 0, stream>>>(tmp, ln_g, ln_bias, out);
}

// Round 6
// 393.058 us; speedup vs baseline: 6.3766x; 1.1045x over previous
//
#include <hip/hip_runtime.h>
#include <math.h>

#define D_STATE 16
#define D_INNER 2048
#define SEQ     2048
#define BSZ     2
#define NTOK    (BSZ*SEQ)   // 4096
#define CH      32           // scan chunk length
#define NCHK    (SEQ/CH)     // 64 chunks per sequence
#define HLOFF   ((size_t)2048 * 4096)   // Hl region offset inside xz (floats)

typedef __bf16 bf16x8 __attribute__((ext_vector_type(8)));
typedef float  floatx4 __attribute__((ext_vector_type(4)));

__device__ __forceinline__ unsigned short f2bf(float f) {  // RNE fp32->bf16
  unsigned int u = __float_as_uint(f);
  u += 0x7fff + ((u >> 16) & 1);
  return (unsigned short)(u >> 16);
}

__device__ __forceinline__ void gload16(const unsigned short* g, unsigned short* l) {
  __builtin_amdgcn_global_load_lds(
      (const __attribute__((address_space(1))) unsigned int*)g,
      (__attribute__((address_space(3))) unsigned int*)l, 16, 0, 0);
}

// ---------------------------------------------------------------------------
// fp32 -> bf16 cast, 4 elems/thread.
// ---------------------------------------------------------------------------
__global__ __launch_bounds__(256) void cast_k(
    const float* __restrict__ src, unsigned short* __restrict__ dst, int n)
{
  int i = (blockIdx.x * 256 + threadIdx.x) * 4;
  if (i < n) {
    float4 v = *(const float4*)(src + i);
    ushort4 o;
    o.x = f2bf(v.x); o.y = f2bf(v.y); o.z = f2bf(v.z); o.w = f2bf(v.w);
    *(ushort4*)(dst + i) = o;
  }
}

// Strided cast: dt_r (cols 0..63 of x_dbl rows of 96) -> bf16, dst stride 64.
__global__ __launch_bounds__(256) void cast_dtr(
    const float* __restrict__ src, unsigned short* __restrict__ dst)
{
  int i = (blockIdx.x * 256 + threadIdx.x) * 4;   // over 4096*64
  int m = i >> 6, col = i & 63;
  float4 v = *(const float4*)(src + (size_t)m * 96 + col);
  ushort4 o;
  o.x = f2bf(v.x); o.y = f2bf(v.y); o.z = f2bf(v.z); o.w = f2bf(v.w);
  *(ushort4*)(dst + (size_t)m * 64 + col) = o;
}

// ---------------------------------------------------------------------------
// bf16 MFMA GEMM: C[m,n] = sum_k A[m,k]*W[n,k]  (fp32 accumulate/output)
// 128x128 tile, 256 thr (4 waves), 4x4 16x16x32 frags/wave, BK=32,
// global_load_lds width-16 staging. LDS col-units swizzled by (row>>1)&3 so
// fragment ds_read_b128 banks collide exactly 2-way (free on CDNA4).
// Split-K: blockIdx.z selects K-slice [z*ksl, (z+1)*ksl), C += z*slicesz.
// MODE 0: plain   MODE 1: softplus(acc + aux[n])   MODE 2: + aux[m*ldc+n]
// ---------------------------------------------------------------------------
template<int MODE>
__global__ __launch_bounds__(256) void mgemm(
    const unsigned short* __restrict__ A, int lda,
    const unsigned short* __restrict__ W, int ldw,
    float* __restrict__ C, int ldc,
    int N, int ksl, const float* __restrict__ aux, size_t slicesz)
{
  __shared__ unsigned short As[128 * 32];
  __shared__ unsigned short Ws[128 * 32];
  const int tid  = threadIdx.x;
  const int wave = tid >> 6, lane = tid & 63;
  const int m0 = blockIdx.y * 128, n0 = blockIdx.x * 128;
  const int k0 = blockIdx.z * ksl;
  C += (size_t)blockIdx.z * slicesz;
  // staging: row within 16-row chunk = lane>>2; swizzled source col-unit
  const int srow = lane >> 2;
  const int scol = ((((lane & 3) + 4) - ((lane >> 3) & 3)) & 3) * 8;
  // fragment coords
  const int fr = lane & 15, fq = lane >> 4;
  const int sw = (fr >> 1) & 3;                 // read-side swizzle key
  const int wm = (wave >> 1) * 64, wn = (wave & 1) * 64;

  const int ar0 = (wave * 2 + 0) * 16 + srow;
  const int ar1 = (wave * 2 + 1) * 16 + srow;
  int wr0 = n0 + ar0; if (wr0 > N - 1) wr0 = N - 1;
  int wr1 = n0 + ar1; if (wr1 > N - 1) wr1 = N - 1;
  const unsigned short* gA0 = A + (size_t)(m0 + ar0) * lda + scol;
  const unsigned short* gA1 = A + (size_t)(m0 + ar1) * lda + scol;
  const unsigned short* gW0 = W + (size_t)wr0 * ldw + scol;
  const unsigned short* gW1 = W + (size_t)wr1 * ldw + scol;
  unsigned short* lA0 = As + (wave * 2 + 0) * 512;
  unsigned short* lA1 = As + (wave * 2 + 1) * 512;
  unsigned short* lW0 = Ws + (wave * 2 + 0) * 512;
  unsigned short* lW1 = Ws + (wave * 2 + 1) * 512;

  floatx4 zero = {0.f, 0.f, 0.f, 0.f};
  floatx4 acc[4][4];
#pragma unroll
  for (int i = 0; i < 4; ++i)
#pragma unroll
    for (int j = 0; j < 4; ++j) acc[i][j] = zero;

  for (int kt = k0; kt < k0 + ksl; kt += 32) {
    __syncthreads();
    gload16(gA0 + kt, lA0);
    gload16(gA1 + kt, lA1);
    gload16(gW0 + kt, lW0);
    gload16(gW1 + kt, lW1);
    __syncthreads();
    bf16x8 af[4], bfr[4];
#pragma unroll
    for (int i = 0; i < 4; ++i) {
      int cuA = ((fq + sw) & 3) * 8;
      af[i]  = *(const bf16x8*)(As + (wm + i * 16 + fr) * 32 + cuA);
      bfr[i] = *(const bf16x8*)(Ws + (wn + i * 16 + fr) * 32 + cuA);
    }
#pragma unroll
    for (int i = 0; i < 4; ++i)
#pragma unroll
      for (int j = 0; j < 4; ++j)
        acc[i][j] = __builtin_amdgcn_mfma_f32_16x16x32_bf16(af[i], bfr[j], acc[i][j], 0, 0, 0);
  }

  // C/D layout: col = lane&15, row = (lane>>4)*4 + reg
#pragma unroll
  for (int i = 0; i < 4; ++i) {
#pragma unroll
    for (int j = 0; j < 4; ++j) {
      int n = n0 + wn + j * 16 + fr;
      if (n < N) {
#pragma unroll
        for (int r = 0; r < 4; ++r) {
          int m = m0 + wm + i * 16 + fq * 4 + r;
          float v = acc[i][j][r];
          if (MODE == 1) { v += aux[n]; v = (v > 20.f) ? v : log1pf(__expf(v)); }
          if (MODE == 2) v += aux[(size_t)m * ldc + n];
          C[(size_t)m * ldc + n] = v;
        }
      }
    }
  }
}

// Sum 8 K-slice partials of x_proj -> xdbl.  4096*96 elems, float4/thread.
__global__ __launch_bounds__(256) void reduce_96(
    const float* __restrict__ p, float* __restrict__ dst)
{
  int i = (blockIdx.x * 256 + threadIdx.x) * 4;   // over 4096*96
  float4 s = *(const float4*)(p + i);
#pragma unroll
  for (int z = 1; z < 8; ++z) {
    float4 v = *(const float4*)(p + (size_t)z * (4096 * 96) + i);
    s.x += v.x; s.y += v.y; s.z += v.z; s.w += v.w;
  }
  *(float4*)(dst + i) = s;
}

// ---------------------------------------------------------------------------
// Depthwise causal conv(4) + bias + SiLU. Writes fp32 xc and bf16 xc_bf.
// ---------------------------------------------------------------------------
__global__ __launch_bounds__(256) void conv_silu_k(
    const float* __restrict__ xz, const float* __restrict__ w,
    const float* __restrict__ b, float* __restrict__ xc,
    unsigned short* __restrict__ xcb)
{
  int idx = blockIdx.x * 256 + threadIdx.x;   // over NTOK*D_INNER
  int e  = idx & (D_INNER - 1);
  int bl = idx >> 11;                          // b*SEQ + l
  int l  = bl & (SEQ - 1);
  float acc = b[e];
#pragma unroll
  for (int k = 0; k < 4; ++k) {
    int ll = l - 3 + k;
    if (ll >= 0)
      acc = fmaf(xz[(size_t)(bl + ll - l) * 4096 + e], w[e * 4 + k], acc);
  }
  float v = acc / (1.f + __expf(-acc));        // silu
  xc[idx] = v;
  xcb[idx] = f2bf(v);
}

// ---------------------------------------------------------------------------
// Chunked selective scan, all 16 states per thread.
// thread t = (b*NCHK + c)*2048 + d.  P/Hl carved into dead xi half of xz.
// ---------------------------------------------------------------------------
__global__ __launch_bounds__(256) void scan_p1(
    const float* __restrict__ A_log,
    const float* __restrict__ x_dbl, const float* __restrict__ xc,
    const float* __restrict__ dt, float* __restrict__ xz)
{
  const int t = blockIdx.x * 256 + threadIdx.x;
  const int d = t & 2047;
  const int c = (t >> 11) & (NCHK - 1);
  const int b = t >> 17;
  const size_t tok0 = (size_t)b * SEQ + c * CH;
  const float* xd = x_dbl + tok0 * 96;

  float Ac[16];
  {
    float4 a0 = *(const float4*)(A_log + d * 16);
    float4 a1 = *(const float4*)(A_log + d * 16 + 4);
    float4 a2 = *(const float4*)(A_log + d * 16 + 8);
    float4 a3 = *(const float4*)(A_log + d * 16 + 12);
    Ac[0]=-__expf(a0.x); Ac[1]=-__expf(a0.y); Ac[2]=-__expf(a0.z); Ac[3]=-__expf(a0.w);
    Ac[4]=-__expf(a1.x); Ac[5]=-__expf(a1.y); Ac[6]=-__expf(a1.z); Ac[7]=-__expf(a1.w);
    Ac[8]=-__expf(a2.x); Ac[9]=-__expf(a2.y); Ac[10]=-__expf(a2.z); Ac[11]=-__expf(a2.w);
    Ac[12]=-__expf(a3.x); Ac[13]=-__expf(a3.y); Ac[14]=-__expf(a3.z); Ac[15]=-__expf(a3.w);
  }

  float p[16], h[16];
#pragma unroll
  for (int s = 0; s < 16; ++s) { p[s] = 1.f; h[s] = 0.f; }

  for (int l = 0; l < CH; ++l) {
    float dtv = dt[(tok0 + l) * 2048 + d];
    float uv  = xc[(tok0 + l) * 2048 + d];
    float du  = dtv * uv;
    float Bv[16];
#pragma unroll
    for (int j = 0; j < 4; ++j) {
      float4 bb = *(const float4*)(xd + l * 96 + 64 + j * 4);
      Bv[j*4+0]=bb.x; Bv[j*4+1]=bb.y; Bv[j*4+2]=bb.z; Bv[j*4+3]=bb.w;
    }
#pragma unroll
    for (int s = 0; s < 16; ++s) {
      float dA = __expf(dtv * Ac[s]);
      p[s] *= dA;
      h[s] = fmaf(dA, h[s], du * Bv[s]);
    }
  }

  float* pp = xz + ((size_t)(t >> 7)) * 4096 + ((t << 4) & 2047);
#pragma unroll
  for (int j = 0; j < 4; ++j) {
    *(float4*)(pp + j * 4)         = make_float4(p[j*4], p[j*4+1], p[j*4+2], p[j*4+3]);
    *(float4*)(pp + HLOFF + j * 4) = make_float4(h[j*4], h[j*4+1], h[j*4+2], h[j*4+3]);
  }
}

// Sequential fix-up over chunks: overwrite Hl[c] with chunk-entry state hin[c].
__global__ __launch_bounds__(256) void scan_fix(float* __restrict__ xz)
{
  int tid = blockIdx.x * 256 + threadIdx.x;  // (b*2048+d)*16+s
  int s = tid & 15;
  int d = (tid >> 4) & 2047;
  int b = tid >> 15;
  float h = 0.f;
  for (int c = 0; c < NCHK; ++c) {
    size_t idx = ((((size_t)(b * NCHK + c) * 2048) + d) * 16) + s;
    size_t addr = (idx >> 11) * 4096 + (idx & 2047);
    float p  = xz[addr];
    float hl = xz[addr + HLOFF];
    xz[addr + HLOFF] = h;               // hin for chunk c
    h = fmaf(p, h, hl);
  }
}

__global__ __launch_bounds__(256) void scan_p2(
    const float* __restrict__ A_log, const float* __restrict__ Dvec,
    const float* __restrict__ x_dbl, const float* __restrict__ xc,
    const float* __restrict__ xz, const float* __restrict__ dt,
    unsigned short* __restrict__ ybf)
{
  const int t = blockIdx.x * 256 + threadIdx.x;
  const int d = t & 2047;
  const int c = (t >> 11) & (NCHK - 1);
  const int b = t >> 17;
  const size_t tok0 = (size_t)b * SEQ + c * CH;
  const float* xd = x_dbl + tok0 * 96;
  const float Dd = Dvec[d];

  float Ac[16];
  {
    float4 a0 = *(const float4*)(A_log + d * 16);
    float4 a1 = *(const float4*)(A_log + d * 16 + 4);
    float4 a2 = *(const float4*)(A_log + d * 16 + 8);
    float4 a3 = *(const float4*)(A_log + d * 16 + 12);
    Ac[0]=-__expf(a0.x); Ac[1]=-__expf(a0.y); Ac[2]=-__expf(a0.z); Ac[3]=-__expf(a0.w);
    Ac[4]=-__expf(a1.x); Ac[5]=-__expf(a1.y); Ac[6]=-__expf(a1.z); Ac[7]=-__expf(a1.w);
    Ac[8]=-__expf(a2.x); Ac[9]=-__expf(a2.y); Ac[10]=-__expf(a2.z); Ac[11]=-__expf(a2.w);
    Ac[12]=-__expf(a3.x); Ac[13]=-__expf(a3.y); Ac[14]=-__expf(a3.z); Ac[15]=-__expf(a3.w);
  }

  const float* pp = xz + ((size_t)(t >> 7)) * 4096 + ((t << 4) & 2047);
  float h[16];
#pragma unroll
  for (int j = 0; j < 4; ++j) {
    float4 hh = *(const float4*)(pp + HLOFF + j * 4);
    h[j*4+0]=hh.x; h[j*4+1]=hh.y; h[j*4+2]=hh.z; h[j*4+3]=hh.w;
  }

  for (int l = 0; l < CH; ++l) {
    float dtv = dt[(tok0 + l) * 2048 + d];
    float uv  = xc[(tok0 + l) * 2048 + d];
    float zv  = xz[(tok0 + l) * 4096 + 2048 + d];
    float du  = dtv * uv;
    float Bv[16], Cv[16];
#pragma unroll
    for (int j = 0; j < 4; ++j) {
      float4 bb = *(const float4*)(xd + l * 96 + 64 + j * 4);
      float4 cc = *(const float4*)(xd + l * 96 + 80 + j * 4);
      Bv[j*4+0]=bb.x; Bv[j*4+1]=bb.y; Bv[j*4+2]=bb.z; Bv[j*4+3]=bb.w;
      Cv[j*4+0]=cc.x; Cv[j*4+1]=cc.y; Cv[j*4+2]=cc.z; Cv[j*4+3]=cc.w;
    }
    float y = 0.f;
#pragma unroll
    for (int s = 0; s < 16; ++s) {
      float dA = __expf(dtv * Ac[s]);
      h[s] = fmaf(dA, h[s], du * Bv[s]);
      y = fmaf(h[s], Cv[s], y);
    }
    y = fmaf(Dd, uv, y);
    y *= zv / (1.f + __expf(-zv));
    ybf[(tok0 + l) * 2048 + d] = f2bf(y);
  }
}

// ---------------------------------------------------------------------------
// Fused: v = p0 + p1 + x  (out_proj split-K reduce + residual), then LN.
// One block (256 thr) per row of 1024.
// ---------------------------------------------------------------------------
__global__ __launch_bounds__(256) void ln2_k(
    const float* __restrict__ p0, const float* __restrict__ p1,
    const float* __restrict__ x, const float* __restrict__ g,
    const float* __restrict__ bb, float* __restrict__ out)
{
  int row = blockIdx.x;
  size_t off = (size_t)row * 1024;
  float4 a = ((const float4*)(p0 + off))[threadIdx.x];
  float4 b = ((const float4*)(p1 + off))[threadIdx.x];
  float4 c = ((const float4*)(x  + off))[threadIdx.x];
  float4 v;
  v.x = a.x + b.x + c.x; v.y = a.y + b.y + c.y;
  v.z = a.z + b.z + c.z; v.w = a.w + b.w + c.w;
  float s  = v.x + v.y + v.z + v.w;
  float sq = v.x * v.x + v.y * v.y + v.z * v.z + v.w * v.w;
#pragma unroll
  for (int o = 32; o >= 1; o >>= 1) {
    s  += __shfl_xor(s,  o, 64);
    sq += __shfl_xor(sq, o, 64);
  }
  __shared__ float red[8];
  int wid = threadIdx.x >> 6;
  if ((threadIdx.x & 63) == 0) { red[wid] = s; red[4 + wid] = sq; }
  __syncthreads();
  s  = red[0] + red[1] + red[2] + red[3];
  sq = red[4] + red[5] + red[6] + red[7];
  float mu  = s * (1.f / 1024.f);
  float var = sq * (1.f / 1024.f) - mu * mu;
  float r   = rsqrtf(var + 1e-5f);
  int col = threadIdx.x * 4;
  float4 gv = *(const float4*)(g + col);
  float4 bv = *(const float4*)(bb + col);
  float4 o;
  o.x = (v.x - mu) * r * gv.x + bv.x;
  o.y = (v.y - mu) * r * gv.y + bv.y;
  o.z = (v.z - mu) * r * gv.z + bv.z;
  o.w = (v.w - mu) * r * gv.w + bv.w;
  ((float4*)(out + off))[threadIdx.x] = o;
}

// ---------------------------------------------------------------------------
extern "C" void kernel_launch(void* const* d_in, const int* in_sizes, int n_in,
                              void* d_out, int out_size, void* d_ws, size_t ws_size,
                              hipStream_t stream)
{
  const float* x       = (const float*)d_in[0];
  const float* in_proj = (const float*)d_in[1];
  const float* conv_w  = (const float*)d_in[2];
  const float* conv_b  = (const float*)d_in[3];
  const float* x_proj  = (const float*)d_in[4];
  const float* dt_w    = (const float*)d_in[5];
  const float* dt_b    = (const float*)d_in[6];
  const float* A_log   = (const float*)d_in[7];
  const float* Dv      = (const float*)d_in[8];
  const float* out_w   = (const float*)d_in[9];
  const float* ln_g    = (const float*)d_in[10];
  const float* ln_bias = (const float*)d_in[11];
  float* out = (float*)d_out;

  float* ws   = (float*)d_ws;
  float* xz   = ws;                              // NTOK*4096 (xi half -> P/Hl; later out_proj partials)
  float* xc   = xz   + (size_t)NTOK * 4096;      // NTOK*2048
  float* xdbl = xc   + (size_t)NTOK * 2048;      // NTOK*96
  float* dty  = xdbl + (size_t)NTOK * 96;        // NTOK*2048 dt (x_bf + x_proj partials carve)
  unsigned short* xc_bf = (unsigned short*)(dty + (size_t)NTOK * 2048); // NTOK*2048
  unsigned short* y_bf  = xc_bf + (size_t)NTOK * 2048;                  // NTOK*2048
  unsigned short* wbuf  = y_bf  + (size_t)NTOK * 2048;                  // 4096*1024
  unsigned short* x_bf  = (unsigned short*)dty;  // carve (dead until x_proj partials)
  unsigned short* dtr_bf = xc_bf;                // reuse (dead after x_proj mgemm)
  float* pbufx = dty;                            // x_proj partials: 8 * 4096*96 floats
  float* pbufo = xz;                             // out_proj partials: 2 * 4096*1024 floats

  dim3 blk(256);
  // casts for in_proj
  cast_k<<<dim3(NTOK * 1024 / 1024), blk, 0, stream>>>(x, x_bf, NTOK * 1024);
  cast_k<<<dim3(4096 * 1024 / 1024), blk, 0, stream>>>(in_proj, wbuf, 4096 * 1024);
  // 1) in_proj MFMA -> xz fp32
  mgemm<0><<<dim3(32, 32, 1), blk, 0, stream>>>(x_bf, 1024, wbuf, 1024,
                                                xz, 4096, 4096, 1024, nullptr, 0);
  // 2) conv + silu -> xc fp32 + xc_bf
  conv_silu_k<<<dim3((NTOK * D_INNER) / 256), blk, 0, stream>>>(xz, conv_w, conv_b, xc, xc_bf);
  // 3) x_proj MFMA, split-K=8 -> partials in pbufx, reduce -> xdbl
  cast_k<<<dim3(96 * 2048 / 1024), blk, 0, stream>>>(x_proj, wbuf, 96 * 2048);
  mgemm<0><<<dim3(1, 32, 8), blk, 0, stream>>>(xc_bf, 2048, wbuf, 2048,
                                               pbufx, 96, 96, 256, nullptr,
                                               (size_t)4096 * 96);
  reduce_96<<<dim3(4096 * 96 / 1024), blk, 0, stream>>>(pbufx, xdbl);
  // 4) dt_proj + softplus via MFMA (K=64)
  cast_dtr<<<dim3(NTOK * 64 / 1024), blk, 0, stream>>>(xdbl, dtr_bf);
  cast_k<<<dim3(2048 * 64 / 1024), blk, 0, stream>>>(dt_w, wbuf, 2048 * 64);
  mgemm<1><<<dim3(16, 32, 1), blk, 0, stream>>>(dtr_bf, 64, wbuf, 64,
                                                dty, 2048, 2048, 64, dt_b, 0);
  // 5) chunked selective scan -> y_bf
  scan_p1 <<<dim3(BSZ * NCHK * 2048 / 256), blk, 0, stream>>>(A_log, xdbl, xc, dty, xz);
  scan_fix<<<dim3(BSZ * 2048 * 16 / 256), blk, 0, stream>>>(xz);
  scan_p2 <<<dim3(BSZ * NCHK * 2048 / 256), blk, 0, stream>>>(A_log, Dv, xdbl, xc, xz, dty, y_bf);
  // 6) out_proj MFMA, split-K=2 -> partials in pbufo (xz dead after scan_p2)
  cast_k<<<dim3(1024 * 2048 / 1024), blk, 0, stream>>>(out_w, wbuf, 1024 * 2048);
  mgemm<0><<<dim3(8, 32, 2), blk, 0, stream>>>(y_bf, 2048, wbuf, 2048,
                                               pbufo, 1024, 1024, 1024, nullptr,
                                               (size_t)4096 * 1024);
  // 7) fused reduce + residual + layernorm -> out
  ln2_k<<<dim3(NTOK), blk, 0, stream>>>(pbufo, pbufo + (size_t)4096 * 1024,
                                        x, ln_g, ln_bias, out);
}

// Round 8
// 379.100 us; speedup vs baseline: 6.6113x; 1.0368x over previous
//
#include <hip/hip_runtime.h>
#include <math.h>

#define D_STATE 16
#define D_INNER 2048
#define SEQ     2048
#define BSZ     2
#define NTOK    (BSZ*SEQ)   // 4096
#define CH      32           // scan chunk length
#define NCHK    (SEQ/CH)     // 64 chunks per sequence
#define PHN     ((size_t)BSZ * NCHK * 2048 * 16)   // 4194304 floats per P/Hl plane

typedef __bf16 bf16x8 __attribute__((ext_vector_type(8)));
typedef float  floatx4 __attribute__((ext_vector_type(4)));

__device__ __forceinline__ unsigned short f2bf(float f) {  // RNE fp32->bf16
  unsigned int u = __float_as_uint(f);
  u += 0x7fff + ((u >> 16) & 1);
  return (unsigned short)(u >> 16);
}
__device__ __forceinline__ float bf2f(unsigned short u) {
  return __uint_as_float((unsigned int)u << 16);
}

__device__ __forceinline__ void gload16(const unsigned short* g, unsigned short* l) {
  __builtin_amdgcn_global_load_lds(
      (const __attribute__((address_space(1))) unsigned int*)g,
      (__attribute__((address_space(3))) unsigned int*)l, 16, 0, 0);
}

// ---------------------------------------------------------------------------
// fp32 -> bf16 cast, 4 elems/thread.
// ---------------------------------------------------------------------------
__global__ __launch_bounds__(256) void cast_k(
    const float* __restrict__ src, unsigned short* __restrict__ dst, int n)
{
  int i = (blockIdx.x * 256 + threadIdx.x) * 4;
  if (i < n) {
    float4 v = *(const float4*)(src + i);
    ushort4 o;
    o.x = f2bf(v.x); o.y = f2bf(v.y); o.z = f2bf(v.z); o.w = f2bf(v.w);
    *(ushort4*)(dst + i) = o;
  }
}

// Two casts in one dispatch (x -> x_bf, in_proj_w -> wbuf).
__global__ __launch_bounds__(256) void cast2_k(
    const float* __restrict__ s1, unsigned short* __restrict__ d1, int n1,
    const float* __restrict__ s2, unsigned short* __restrict__ d2, int n2)
{
  int i = (blockIdx.x * 256 + threadIdx.x) * 4;
  const float* s; unsigned short* d;
  if (i < n1) { s = s1 + i; d = d1 + i; }
  else if (i < n1 + n2) { s = s2 + (i - n1); d = d2 + (i - n1); }
  else return;
  float4 v = *(const float4*)s;
  ushort4 o;
  o.x = f2bf(v.x); o.y = f2bf(v.y); o.z = f2bf(v.z); o.w = f2bf(v.w);
  *(ushort4*)d = o;
}

// Fused: sum 8 K-slice partials of x_proj -> xdbl fp32, and cast cols 0..63
// (dt_r) to bf16 (stride 64).  dtr dst MUST be a dead buffer (x_bf).
__global__ __launch_bounds__(256) void redcast_k(
    const float* __restrict__ p, float* __restrict__ dst,
    unsigned short* __restrict__ dtr)
{
  int i = (blockIdx.x * 256 + threadIdx.x) * 4;   // over 4096*96, col%4==0
  float4 s = *(const float4*)(p + i);
#pragma unroll
  for (int z = 1; z < 8; ++z) {
    float4 v = *(const float4*)(p + (size_t)z * (4096 * 96) + i);
    s.x += v.x; s.y += v.y; s.z += v.z; s.w += v.w;
  }
  *(float4*)(dst + i) = s;
  int m = i / 96, col = i - m * 96;
  if (col < 64) {
    ushort4 o;
    o.x = f2bf(s.x); o.y = f2bf(s.y); o.z = f2bf(s.z); o.w = f2bf(s.w);
    *(ushort4*)(dtr + (size_t)m * 64 + col) = o;
  }
}

// ---------------------------------------------------------------------------
// bf16 MFMA GEMM: C[m,n] = sum_k A[m,k]*W[n,k]  (fp32 accumulate)
// 128x128 tile, 256 thr (4 waves), 4x4 16x16x32 frags/wave, BK=32,
// global_load_lds width-16 staging, 2-way-conflict LDS swizzle.
// Split-K via blockIdx.z (slice ksl, C += z*slicesz).
// MODE 0: fp32 out   MODE 1: fp32 softplus(acc+aux[n])   MODE 3: bf16 out
// ---------------------------------------------------------------------------
template<int MODE>
__global__ __launch_bounds__(256) void mgemm(
    const unsigned short* __restrict__ A, int lda,
    const unsigned short* __restrict__ W, int ldw,
    void* __restrict__ Cv_, int ldc,
    int N, int ksl, const float* __restrict__ aux, size_t slicesz)
{
  __shared__ unsigned short As[128 * 32];
  __shared__ unsigned short Ws[128 * 32];
  const int tid  = threadIdx.x;
  const int wave = tid >> 6, lane = tid & 63;
  const int m0 = blockIdx.y * 128, n0 = blockIdx.x * 128;
  const int k0 = blockIdx.z * ksl;
  const int srow = lane >> 2;
  const int scol = ((((lane & 3) + 4) - ((lane >> 3) & 3)) & 3) * 8;
  const int fr = lane & 15, fq = lane >> 4;
  const int sw = (fr >> 1) & 3;
  const int wm = (wave >> 1) * 64, wn = (wave & 1) * 64;

  const int ar0 = (wave * 2 + 0) * 16 + srow;
  const int ar1 = (wave * 2 + 1) * 16 + srow;
  int wr0 = n0 + ar0; if (wr0 > N - 1) wr0 = N - 1;
  int wr1 = n0 + ar1; if (wr1 > N - 1) wr1 = N - 1;
  const unsigned short* gA0 = A + (size_t)(m0 + ar0) * lda + scol;
  const unsigned short* gA1 = A + (size_t)(m0 + ar1) * lda + scol;
  const unsigned short* gW0 = W + (size_t)wr0 * ldw + scol;
  const unsigned short* gW1 = W + (size_t)wr1 * ldw + scol;
  unsigned short* lA0 = As + (wave * 2 + 0) * 512;
  unsigned short* lA1 = As + (wave * 2 + 1) * 512;
  unsigned short* lW0 = Ws + (wave * 2 + 0) * 512;
  unsigned short* lW1 = Ws + (wave * 2 + 1) * 512;

  floatx4 zero = {0.f, 0.f, 0.f, 0.f};
  floatx4 acc[4][4];
#pragma unroll
  for (int i = 0; i < 4; ++i)
#pragma unroll
    for (int j = 0; j < 4; ++j) acc[i][j] = zero;

  for (int kt = k0; kt < k0 + ksl; kt += 32) {
    __syncthreads();
    gload16(gA0 + kt, lA0);
    gload16(gA1 + kt, lA1);
    gload16(gW0 + kt, lW0);
    gload16(gW1 + kt, lW1);
    __syncthreads();
    bf16x8 af[4], bfr[4];
#pragma unroll
    for (int i = 0; i < 4; ++i) {
      int cuA = ((fq + sw) & 3) * 8;
      af[i]  = *(const bf16x8*)(As + (wm + i * 16 + fr) * 32 + cuA);
      bfr[i] = *(const bf16x8*)(Ws + (wn + i * 16 + fr) * 32 + cuA);
    }
#pragma unroll
    for (int i = 0; i < 4; ++i)
#pragma unroll
      for (int j = 0; j < 4; ++j)
        acc[i][j] = __builtin_amdgcn_mfma_f32_16x16x32_bf16(af[i], bfr[j], acc[i][j], 0, 0, 0);
  }

  // C/D layout: col = lane&15, row = (lane>>4)*4 + reg
#pragma unroll
  for (int i = 0; i < 4; ++i) {
#pragma unroll
    for (int j = 0; j < 4; ++j) {
      int n = n0 + wn + j * 16 + fr;
      if (n < N) {
#pragma unroll
        for (int r = 0; r < 4; ++r) {
          int m = m0 + wm + i * 16 + fq * 4 + r;
          float v = acc[i][j][r];
          if (MODE == 1) { v += aux[n]; v = (v > 20.f) ? v : log1pf(__expf(v)); }
          if (MODE == 3) {
            ((unsigned short*)Cv_)[(size_t)m * ldc + n] = f2bf(v);
          } else {
            float* C = (float*)Cv_ + (size_t)blockIdx.z * slicesz;
            C[(size_t)m * ldc + n] = v;
          }
        }
      }
    }
  }
}

// ---------------------------------------------------------------------------
// Depthwise causal conv(4) + bias + SiLU. bf16 in (xi half of xz_bf), bf16 out.
// 4 channels per thread.
// ---------------------------------------------------------------------------
__global__ __launch_bounds__(256) void conv_silu_k(
    const unsigned short* __restrict__ xzb, const float* __restrict__ w,
    const float* __restrict__ b, unsigned short* __restrict__ xcb)
{
  int gid = blockIdx.x * 256 + threadIdx.x;    // over NTOK*2048/4
  int e4 = (gid * 4) & 2047;
  int bl = gid >> 9;                            // b*SEQ + l
  int l  = bl & (SEQ - 1);
  float4 acc = *(const float4*)(b + e4);
  float4 w0 = *(const float4*)(w + (e4 + 0) * 4);
  float4 w1 = *(const float4*)(w + (e4 + 1) * 4);
  float4 w2 = *(const float4*)(w + (e4 + 2) * 4);
  float4 w3 = *(const float4*)(w + (e4 + 3) * 4);
  const float* w0p = (const float*)&w0;
  const float* w1p = (const float*)&w1;
  const float* w2p = (const float*)&w2;
  const float* w3p = (const float*)&w3;
#pragma unroll
  for (int k = 0; k < 4; ++k) {
    int ll = l - 3 + k;
    if (ll >= 0) {
      ushort4 xv = *(const ushort4*)(xzb + (size_t)(bl - 3 + k) * 4096 + e4);
      acc.x = fmaf(bf2f(xv.x), w0p[k], acc.x);
      acc.y = fmaf(bf2f(xv.y), w1p[k], acc.y);
      acc.z = fmaf(bf2f(xv.z), w2p[k], acc.z);
      acc.w = fmaf(bf2f(xv.w), w3p[k], acc.w);
    }
  }
  ushort4 o;
  o.x = f2bf(acc.x / (1.f + __expf(-acc.x)));
  o.y = f2bf(acc.y / (1.f + __expf(-acc.y)));
  o.z = f2bf(acc.z / (1.f + __expf(-acc.z)));
  o.w = f2bf(acc.w / (1.f + __expf(-acc.w)));
  *(ushort4*)(xcb + (size_t)gid * 4) = o;
}

// ---------------------------------------------------------------------------
// Chunked selective scan, all 16 states per thread.
// thread t = (b*NCHK + c)*2048 + d.  P at PH[t*16+s], Hl/hin at PH[PHN+t*16+s].
// ---------------------------------------------------------------------------
__global__ __launch_bounds__(256) void scan_p1(
    const float* __restrict__ A_log,
    const float* __restrict__ x_dbl, const unsigned short* __restrict__ xcb,
    const float* __restrict__ dt, float* __restrict__ PH)
{
  const int t = blockIdx.x * 256 + threadIdx.x;
  const int d = t & 2047;
  const int c = (t >> 11) & (NCHK - 1);
  const int b = t >> 17;
  const size_t tok0 = (size_t)b * SEQ + c * CH;
  const float* xd = x_dbl + tok0 * 96;

  float Ac[16];
  {
    float4 a0 = *(const float4*)(A_log + d * 16);
    float4 a1 = *(const float4*)(A_log + d * 16 + 4);
    float4 a2 = *(const float4*)(A_log + d * 16 + 8);
    float4 a3 = *(const float4*)(A_log + d * 16 + 12);
    Ac[0]=-__expf(a0.x); Ac[1]=-__expf(a0.y); Ac[2]=-__expf(a0.z); Ac[3]=-__expf(a0.w);
    Ac[4]=-__expf(a1.x); Ac[5]=-__expf(a1.y); Ac[6]=-__expf(a1.z); Ac[7]=-__expf(a1.w);
    Ac[8]=-__expf(a2.x); Ac[9]=-__expf(a2.y); Ac[10]=-__expf(a2.z); Ac[11]=-__expf(a2.w);
    Ac[12]=-__expf(a3.x); Ac[13]=-__expf(a3.y); Ac[14]=-__expf(a3.z); Ac[15]=-__expf(a3.w);
  }

  float p[16], h[16];
#pragma unroll
  for (int s = 0; s < 16; ++s) { p[s] = 1.f; h[s] = 0.f; }

  for (int l = 0; l < CH; ++l) {
    float dtv = dt[(tok0 + l) * 2048 + d];
    float uv  = bf2f(xcb[(tok0 + l) * 2048 + d]);
    float du  = dtv * uv;
    float Bv[16];
#pragma unroll
    for (int j = 0; j < 4; ++j) {
      float4 bb = *(const float4*)(xd + l * 96 + 64 + j * 4);
      Bv[j*4+0]=bb.x; Bv[j*4+1]=bb.y; Bv[j*4+2]=bb.z; Bv[j*4+3]=bb.w;
    }
#pragma unroll
    for (int s = 0; s < 16; ++s) {
      float dA = __expf(dtv * Ac[s]);
      p[s] *= dA;
      h[s] = fmaf(dA, h[s], du * Bv[s]);
    }
  }

  float* pp = PH + (size_t)t * 16;
#pragma unroll
  for (int j = 0; j < 4; ++j) {
    *(float4*)(pp + j * 4)       = make_float4(p[j*4], p[j*4+1], p[j*4+2], p[j*4+3]);
    *(float4*)(pp + PHN + j * 4) = make_float4(h[j*4], h[j*4+1], h[j*4+2], h[j*4+3]);
  }
}

// Sequential fix-up over chunks: overwrite Hl[c] with chunk-entry state hin[c].
__global__ __launch_bounds__(256) void scan_fix(float* __restrict__ PH)
{
  int tid = blockIdx.x * 256 + threadIdx.x;  // (b*2048+d)*16+s
  int s = tid & 15;
  int d = (tid >> 4) & 2047;
  int b = tid >> 15;
  float h = 0.f;
  for (int c = 0; c < NCHK; ++c) {
    size_t idx = ((((size_t)(b * NCHK + c) * 2048) + d) * 16) + s;
    float p  = PH[idx];
    float hl = PH[idx + PHN];
    PH[idx + PHN] = h;               // hin for chunk c
    h = fmaf(p, h, hl);
  }
}

__global__ __launch_bounds__(256) void scan_p2(
    const float* __restrict__ A_log, const float* __restrict__ Dvec,
    const float* __restrict__ x_dbl, const unsigned short* __restrict__ xcb,
    const unsigned short* __restrict__ xzb, const float* __restrict__ PH,
    const float* __restrict__ dt, unsigned short* __restrict__ ybf)
{
  const int t = blockIdx.x * 256 + threadIdx.x;
  const int d = t & 2047;
  const int c = (t >> 11) & (NCHK - 1);
  const int b = t >> 17;
  const size_t tok0 = (size_t)b * SEQ + c * CH;
  const float* xd = x_dbl + tok0 * 96;
  const float Dd = Dvec[d];

  float Ac[16];
  {
    float4 a0 = *(const float4*)(A_log + d * 16);
    float4 a1 = *(const float4*)(A_log + d * 16 + 4);
    float4 a2 = *(const float4*)(A_log + d * 16 + 8);
    float4 a3 = *(const float4*)(A_log + d * 16 + 12);
    Ac[0]=-__expf(a0.x); Ac[1]=-__expf(a0.y); Ac[2]=-__expf(a0.z); Ac[3]=-__expf(a0.w);
    Ac[4]=-__expf(a1.x); Ac[5]=-__expf(a1.y); Ac[6]=-__expf(a1.z); Ac[7]=-__expf(a1.w);
    Ac[8]=-__expf(a2.x); Ac[9]=-__expf(a2.y); Ac[10]=-__expf(a2.z); Ac[11]=-__expf(a2.w);
    Ac[12]=-__expf(a3.x); Ac[13]=-__expf(a3.y); Ac[14]=-__expf(a3.z); Ac[15]=-__expf(a3.w);
  }

  const float* pp = PH + (size_t)t * 16;
  float h[16];
#pragma unroll
  for (int j = 0; j < 4; ++j) {
    float4 hh = *(const float4*)(pp + PHN + j * 4);
    h[j*4+0]=hh.x; h[j*4+1]=hh.y; h[j*4+2]=hh.z; h[j*4+3]=hh.w;
  }

  for (int l = 0; l < CH; ++l) {
    float dtv = dt[(tok0 + l) * 2048 + d];
    float uv  = bf2f(xcb[(tok0 + l) * 2048 + d]);
    float zv  = bf2f(xzb[(tok0 + l) * 4096 + 2048 + d]);
    float du  = dtv * uv;
    float Bv[16], Cv[16];
#pragma unroll
    for (int j = 0; j < 4; ++j) {
      float4 bb = *(const float4*)(xd + l * 96 + 64 + j * 4);
      float4 cc = *(const float4*)(xd + l * 96 + 80 + j * 4);
      Bv[j*4+0]=bb.x; Bv[j*4+1]=bb.y; Bv[j*4+2]=bb.z; Bv[j*4+3]=bb.w;
      Cv[j*4+0]=cc.x; Cv[j*4+1]=cc.y; Cv[j*4+2]=cc.z; Cv[j*4+3]=cc.w;
    }
    float y = 0.f;
#pragma unroll
    for (int s = 0; s < 16; ++s) {
      float dA = __expf(dtv * Ac[s]);
      h[s] = fmaf(dA, h[s], du * Bv[s]);
      y = fmaf(h[s], Cv[s], y);
    }
    y = fmaf(Dd, uv, y);
    y *= zv / (1.f + __expf(-zv));
    ybf[(tok0 + l) * 2048 + d] = f2bf(y);
  }
}

// ---------------------------------------------------------------------------
// Fused: v = p0 + p1 + x  (out_proj split-K reduce + residual), then LN.
// One block (256 thr) per row of 1024.
// ---------------------------------------------------------------------------
__global__ __launch_bounds__(256) void ln2_k(
    const float* __restrict__ p0, const float* __restrict__ p1,
    const float* __restrict__ x, const float* __restrict__ g,
    const float* __restrict__ bb, float* __restrict__ out)
{
  int row = blockIdx.x;
  size_t off = (size_t)row * 1024;
  float4 a = ((const float4*)(p0 + off))[threadIdx.x];
  float4 b = ((const float4*)(p1 + off))[threadIdx.x];
  float4 c = ((const float4*)(x  + off))[threadIdx.x];
  float4 v;
  v.x = a.x + b.x + c.x; v.y = a.y + b.y + c.y;
  v.z = a.z + b.z + c.z; v.w = a.w + b.w + c.w;
  float s  = v.x + v.y + v.z + v.w;
  float sq = v.x * v.x + v.y * v.y + v.z * v.z + v.w * v.w;
#pragma unroll
  for (int o = 32; o >= 1; o >>= 1) {
    s  += __shfl_xor(s,  o, 64);
    sq += __shfl_xor(sq, o, 64);
  }
  __shared__ float red[8];
  int wid = threadIdx.x >> 6;
  if ((threadIdx.x & 63) == 0) { red[wid] = s; red[4 + wid] = sq; }
  __syncthreads();
  s  = red[0] + red[1] + red[2] + red[3];
  sq = red[4] + red[5] + red[6] + red[7];
  float mu  = s * (1.f / 1024.f);
  float var = sq * (1.f / 1024.f) - mu * mu;
  float r   = rsqrtf(var + 1e-5f);
  int col = threadIdx.x * 4;
  float4 gv = *(const float4*)(g + col);
  float4 bv = *(const float4*)(bb + col);
  float4 o;
  o.x = (v.x - mu) * r * gv.x + bv.x;
  o.y = (v.y - mu) * r * gv.y + bv.y;
  o.z = (v.z - mu) * r * gv.z + bv.z;
  o.w = (v.w - mu) * r * gv.w + bv.w;
  ((float4*)(out + off))[threadIdx.x] = o;
}

// ---------------------------------------------------------------------------
extern "C" void kernel_launch(void* const* d_in, const int* in_sizes, int n_in,
                              void* d_out, int out_size, void* d_ws, size_t ws_size,
                              hipStream_t stream)
{
  const float* x       = (const float*)d_in[0];
  const float* in_proj = (const float*)d_in[1];
  const float* conv_w  = (const float*)d_in[2];
  const float* conv_b  = (const float*)d_in[3];
  const float* x_proj  = (const float*)d_in[4];
  const float* dt_w    = (const float*)d_in[5];
  const float* dt_b    = (const float*)d_in[6];
  const float* A_log   = (const float*)d_in[7];
  const float* Dv      = (const float*)d_in[8];
  const float* out_w   = (const float*)d_in[9];
  const float* ln_g    = (const float*)d_in[10];
  const float* ln_bias = (const float*)d_in[11];
  float* out = (float*)d_out;

  char* w8 = (char*)d_ws;
  unsigned short* xz_bf = (unsigned short*)w8;                 // 33.55 MB
  unsigned short* xc_bf = (unsigned short*)(w8 + 33554432);    // 16.78 MB
  float*          xdbl  = (float*)(w8 + 50331648);             //  1.57 MB
  float*          dty   = (float*)(w8 + 51904512);             // 33.55 MB
  unsigned short* y_bf  = (unsigned short*)(w8 + 85458944);    // 16.78 MB
  unsigned short* wbuf  = (unsigned short*)(w8 + 102236160);   //  8.39 MB
  unsigned short* x_bf  = (unsigned short*)(w8 + 110624768);   //  8.39 MB
  float*          pbufx = (float*)(w8 + 119013376);            // 12.58 MB
  float*          PH    = (float*)(w8 + 131596288);            // 33.55 MB
  float*          pbufo = (float*)xz_bf;                       // alias (exact fit)

  dim3 blk(256);
  // 0) casts for in_proj (x and weight) in one dispatch
  cast2_k<<<dim3(2 * NTOK * 1024 / 1024), blk, 0, stream>>>(
      x, x_bf, NTOK * 1024, in_proj, wbuf, 4096 * 1024);
  // 1) in_proj MFMA -> xz_bf (bf16 out)
  mgemm<3><<<dim3(32, 32, 1), blk, 0, stream>>>(x_bf, 1024, wbuf, 1024,
                                                xz_bf, 4096, 4096, 1024, nullptr, 0);
  // 2) conv + silu -> xc_bf
  conv_silu_k<<<dim3((NTOK * D_INNER / 4) / 256), blk, 0, stream>>>(
      xz_bf, conv_w, conv_b, xc_bf);
  // 3) x_proj MFMA, split-K=8 -> partials; fused reduce + dt_r cast into x_bf
  //    (x_bf is DEAD after the in_proj mgemm; xc_bf stays live for the scan)
  cast_k<<<dim3(96 * 2048 / 1024), blk, 0, stream>>>(x_proj, wbuf, 96 * 2048);
  mgemm<0><<<dim3(1, 32, 8), blk, 0, stream>>>(xc_bf, 2048, wbuf, 2048,
                                               pbufx, 96, 96, 256, nullptr,
                                               (size_t)4096 * 96);
  redcast_k<<<dim3(4096 * 96 / 1024), blk, 0, stream>>>(pbufx, xdbl, x_bf /*dtr*/);
  // 4) dt_proj + softplus via MFMA (K=64), A = dtr in x_bf (lda=64)
  cast_k<<<dim3(2048 * 64 / 1024), blk, 0, stream>>>(dt_w, wbuf, 2048 * 64);
  mgemm<1><<<dim3(16, 32, 1), blk, 0, stream>>>(x_bf /*dtr*/, 64, wbuf, 64,
                                                dty, 2048, 2048, 64, dt_b, 0);
  // 5) chunked selective scan -> y_bf
  scan_p1 <<<dim3(BSZ * NCHK * 2048 / 256), blk, 0, stream>>>(A_log, xdbl, xc_bf, dty, PH);
  scan_fix<<<dim3(BSZ * 2048 * 16 / 256), blk, 0, stream>>>(PH);
  scan_p2 <<<dim3(BSZ * NCHK * 2048 / 256), blk, 0, stream>>>(A_log, Dv, xdbl, xc_bf,
                                                              xz_bf, PH, dty, y_bf);
  // 6) out_proj MFMA, split-K=2 -> partials in pbufo (xz_bf dead after scan_p2)
  cast_k<<<dim3(1024 * 2048 / 1024), blk, 0, stream>>>(out_w, wbuf, 1024 * 2048);
  mgemm<0><<<dim3(8, 32, 2), blk, 0, stream>>>(y_bf, 2048, wbuf, 2048,
                                               pbufo, 1024, 1024, 1024, nullptr,
                                               (size_t)4096 * 1024);
  // 7) fused reduce + residual + layernorm -> out
  ln2_k<<<dim3(NTOK), blk, 0, stream>>>(pbufo, pbufo + (size_t)4096 * 1024,
                                        x, ln_g, ln_bias, out);
}

// Round 9
// 362.515 us; speedup vs baseline: 6.9138x; 1.0458x over previous
//
#include <hip/hip_runtime.h>
#include <math.h>

#define D_STATE 16
#define D_INNER 2048
#define SEQ     2048
#define BSZ     2
#define NTOK    (BSZ*SEQ)   // 4096
#define CH      32           // scan chunk length
#define NCHK    (SEQ/CH)     // 64 chunks per sequence
#define PHN     ((size_t)BSZ * NCHK * 2048 * 16)   // floats per P/Hl plane

typedef __bf16 bf16x8 __attribute__((ext_vector_type(8)));
typedef float  floatx4 __attribute__((ext_vector_type(4)));

__device__ __forceinline__ unsigned short f2bf(float f) {  // RNE fp32->bf16
  unsigned int u = __float_as_uint(f);
  u += 0x7fff + ((u >> 16) & 1);
  return (unsigned short)(u >> 16);
}
__device__ __forceinline__ float bf2f(unsigned short u) {
  return __uint_as_float((unsigned int)u << 16);
}

__device__ __forceinline__ void gload16(const unsigned short* g, unsigned short* l) {
  __builtin_amdgcn_global_load_lds(
      (const __attribute__((address_space(1))) unsigned int*)g,
      (__attribute__((address_space(3))) unsigned int*)l, 16, 0, 0);
}

// ---------------------------------------------------------------------------
// Mega-cast: x + 4 weight matrices fp32->bf16 in one dispatch.
// ---------------------------------------------------------------------------
#define N_X   (NTOK*1024)      // 4194304
#define N_WI  (4096*1024)      // 4194304
#define N_WX  (96*2048)        // 196608
#define N_WD  (2048*64)        // 131072
#define N_WO  (1024*2048)      // 2097152
#define N_ALL (N_X+N_WI+N_WX+N_WD+N_WO)   // 10813440

__global__ __launch_bounds__(256) void cast5_k(
    const float* __restrict__ sx, unsigned short* __restrict__ dx,
    const float* __restrict__ swi, unsigned short* __restrict__ dwi,
    const float* __restrict__ swx, unsigned short* __restrict__ dwx,
    const float* __restrict__ swd, unsigned short* __restrict__ dwd,
    const float* __restrict__ swo, unsigned short* __restrict__ dwo)
{
  int i = (blockIdx.x * 256 + threadIdx.x) * 4;
  const float* s; unsigned short* d;
  if      (i < N_X)                  { s = sx  + i;                      d = dx  + i; }
  else if (i < N_X+N_WI)             { s = swi + (i - N_X);              d = dwi + (i - N_X); }
  else if (i < N_X+N_WI+N_WX)        { s = swx + (i - N_X-N_WI);         d = dwx + (i - N_X-N_WI); }
  else if (i < N_X+N_WI+N_WX+N_WD)   { s = swd + (i - N_X-N_WI-N_WX);    d = dwd + (i - N_X-N_WI-N_WX); }
  else if (i < N_ALL)                { s = swo + (i - N_X-N_WI-N_WX-N_WD); d = dwo + (i - N_X-N_WI-N_WX-N_WD); }
  else return;
  float4 v = *(const float4*)s;
  ushort4 o;
  o.x = f2bf(v.x); o.y = f2bf(v.y); o.z = f2bf(v.z); o.w = f2bf(v.w);
  *(ushort4*)d = o;
}

// Fused: sum 8 K-slice partials of x_proj -> xdbl fp32, + dt_r bf16 (stride 64).
__global__ __launch_bounds__(256) void redcast_k(
    const float* __restrict__ p, float* __restrict__ dst,
    unsigned short* __restrict__ dtr)
{
  int i = (blockIdx.x * 256 + threadIdx.x) * 4;   // over 4096*96
  float4 s = *(const float4*)(p + i);
#pragma unroll
  for (int z = 1; z < 8; ++z) {
    float4 v = *(const float4*)(p + (size_t)z * (4096 * 96) + i);
    s.x += v.x; s.y += v.y; s.z += v.z; s.w += v.w;
  }
  *(float4*)(dst + i) = s;
  int m = i / 96, col = i - m * 96;
  if (col < 64) {
    ushort4 o;
    o.x = f2bf(s.x); o.y = f2bf(s.y); o.z = f2bf(s.z); o.w = f2bf(s.w);
    *(ushort4*)(dtr + (size_t)m * 64 + col) = o;
  }
}

// ---------------------------------------------------------------------------
// bf16 MFMA GEMM, BK=64 via two 32-col LDS planes (one barrier pair per 64 K).
// 128x128 tile, 256 thr, 4x4 16x16x32 frags/wave, 2-way-conflict LDS swizzle.
// Split-K via blockIdx.z (slice ksl, fp32 C += z*slicesz). ksl % 64 == 0.
// MODE 0: fp32 out   MODE 1: bf16 softplus(acc+aux[n])   MODE 3: bf16 out
// ---------------------------------------------------------------------------
template<int MODE>
__global__ __launch_bounds__(256) void mgemm(
    const unsigned short* __restrict__ A, int lda,
    const unsigned short* __restrict__ W, int ldw,
    void* __restrict__ Cv_, int ldc,
    int N, int ksl, const float* __restrict__ aux, size_t slicesz)
{
  __shared__ unsigned short As[2][128 * 32];
  __shared__ unsigned short Ws[2][128 * 32];
  const int tid  = threadIdx.x;
  const int wave = tid >> 6, lane = tid & 63;
  const int m0 = blockIdx.y * 128, n0 = blockIdx.x * 128;
  const int k0 = blockIdx.z * ksl;
  const int srow = lane >> 2;
  const int scol = ((((lane & 3) + 4) - ((lane >> 3) & 3)) & 3) * 8;
  const int fr = lane & 15, fq = lane >> 4;
  const int sw = (fr >> 1) & 3;
  const int wm = (wave >> 1) * 64, wn = (wave & 1) * 64;

  const int ar0 = (wave * 2 + 0) * 16 + srow;
  const int ar1 = (wave * 2 + 1) * 16 + srow;
  int wr0 = n0 + ar0; if (wr0 > N - 1) wr0 = N - 1;
  int wr1 = n0 + ar1; if (wr1 > N - 1) wr1 = N - 1;
  const unsigned short* gA0 = A + (size_t)(m0 + ar0) * lda + scol;
  const unsigned short* gA1 = A + (size_t)(m0 + ar1) * lda + scol;
  const unsigned short* gW0 = W + (size_t)wr0 * ldw + scol;
  const unsigned short* gW1 = W + (size_t)wr1 * ldw + scol;
  const int lofs0 = (wave * 2 + 0) * 512;
  const int lofs1 = (wave * 2 + 1) * 512;

  floatx4 zero = {0.f, 0.f, 0.f, 0.f};
  floatx4 acc[4][4];
#pragma unroll
  for (int i = 0; i < 4; ++i)
#pragma unroll
    for (int j = 0; j < 4; ++j) acc[i][j] = zero;

  for (int kt = k0; kt < k0 + ksl; kt += 64) {
    __syncthreads();
    gload16(gA0 + kt,      As[0] + lofs0);
    gload16(gA1 + kt,      As[0] + lofs1);
    gload16(gW0 + kt,      Ws[0] + lofs0);
    gload16(gW1 + kt,      Ws[0] + lofs1);
    gload16(gA0 + kt + 32, As[1] + lofs0);
    gload16(gA1 + kt + 32, As[1] + lofs1);
    gload16(gW0 + kt + 32, Ws[1] + lofs0);
    gload16(gW1 + kt + 32, Ws[1] + lofs1);
    __syncthreads();
#pragma unroll
    for (int kb = 0; kb < 2; ++kb) {
      bf16x8 af[4], bfr[4];
      const int cuA = ((fq + sw) & 3) * 8;
#pragma unroll
      for (int i = 0; i < 4; ++i) {
        af[i]  = *(const bf16x8*)(As[kb] + (wm + i * 16 + fr) * 32 + cuA);
        bfr[i] = *(const bf16x8*)(Ws[kb] + (wn + i * 16 + fr) * 32 + cuA);
      }
#pragma unroll
      for (int i = 0; i < 4; ++i)
#pragma unroll
        for (int j = 0; j < 4; ++j)
          acc[i][j] = __builtin_amdgcn_mfma_f32_16x16x32_bf16(af[i], bfr[j], acc[i][j], 0, 0, 0);
    }
  }

  // C/D layout: col = lane&15, row = (lane>>4)*4 + reg
#pragma unroll
  for (int i = 0; i < 4; ++i) {
#pragma unroll
    for (int j = 0; j < 4; ++j) {
      int n = n0 + wn + j * 16 + fr;
      if (n < N) {
#pragma unroll
        for (int r = 0; r < 4; ++r) {
          int m = m0 + wm + i * 16 + fq * 4 + r;
          float v = acc[i][j][r];
          if (MODE == 1) {
            v += aux[n]; v = (v > 20.f) ? v : log1pf(__expf(v));
            ((unsigned short*)Cv_)[(size_t)m * ldc + n] = f2bf(v);
          } else if (MODE == 3) {
            ((unsigned short*)Cv_)[(size_t)m * ldc + n] = f2bf(v);
          } else {
            float* C = (float*)Cv_ + (size_t)blockIdx.z * slicesz;
            C[(size_t)m * ldc + n] = v;
          }
        }
      }
    }
  }
}

// ---------------------------------------------------------------------------
// Depthwise causal conv(4) + bias + SiLU. bf16 in/out, 4 channels per thread.
// ---------------------------------------------------------------------------
__global__ __launch_bounds__(256) void conv_silu_k(
    const unsigned short* __restrict__ xzb, const float* __restrict__ w,
    const float* __restrict__ b, unsigned short* __restrict__ xcb)
{
  int gid = blockIdx.x * 256 + threadIdx.x;    // over NTOK*2048/4
  int e4 = (gid * 4) & 2047;
  int bl = gid >> 9;                            // b*SEQ + l
  int l  = bl & (SEQ - 1);
  float4 acc = *(const float4*)(b + e4);
  float4 w0 = *(const float4*)(w + (e4 + 0) * 4);
  float4 w1 = *(const float4*)(w + (e4 + 1) * 4);
  float4 w2 = *(const float4*)(w + (e4 + 2) * 4);
  float4 w3 = *(const float4*)(w + (e4 + 3) * 4);
  const float* w0p = (const float*)&w0;
  const float* w1p = (const float*)&w1;
  const float* w2p = (const float*)&w2;
  const float* w3p = (const float*)&w3;
#pragma unroll
  for (int k = 0; k < 4; ++k) {
    int ll = l - 3 + k;
    if (ll >= 0) {
      ushort4 xv = *(const ushort4*)(xzb + (size_t)(bl - 3 + k) * 4096 + e4);
      acc.x = fmaf(bf2f(xv.x), w0p[k], acc.x);
      acc.y = fmaf(bf2f(xv.y), w1p[k], acc.y);
      acc.z = fmaf(bf2f(xv.z), w2p[k], acc.z);
      acc.w = fmaf(bf2f(xv.w), w3p[k], acc.w);
    }
  }
  ushort4 o;
  o.x = f2bf(acc.x / (1.f + __expf(-acc.x)));
  o.y = f2bf(acc.y / (1.f + __expf(-acc.y)));
  o.z = f2bf(acc.z / (1.f + __expf(-acc.z)));
  o.w = f2bf(acc.w / (1.f + __expf(-acc.w)));
  *(ushort4*)(xcb + (size_t)gid * 4) = o;
}

// ---------------------------------------------------------------------------
// Chunked selective scan, all 16 states per thread. dt is bf16 now.
// thread t = (b*NCHK + c)*2048 + d.  P at PH[t*16+s], Hl/hin at +PHN.
// ---------------------------------------------------------------------------
__global__ __launch_bounds__(256) void scan_p1(
    const float* __restrict__ A_log,
    const float* __restrict__ x_dbl, const unsigned short* __restrict__ xcb,
    const unsigned short* __restrict__ dtb, float* __restrict__ PH)
{
  const int t = blockIdx.x * 256 + threadIdx.x;
  const int d = t & 2047;
  const int c = (t >> 11) & (NCHK - 1);
  const int b = t >> 17;
  const size_t tok0 = (size_t)b * SEQ + c * CH;
  const float* xd = x_dbl + tok0 * 96;

  float Ac[16];
  {
    float4 a0 = *(const float4*)(A_log + d * 16);
    float4 a1 = *(const float4*)(A_log + d * 16 + 4);
    float4 a2 = *(const float4*)(A_log + d * 16 + 8);
    float4 a3 = *(const float4*)(A_log + d * 16 + 12);
    Ac[0]=-__expf(a0.x); Ac[1]=-__expf(a0.y); Ac[2]=-__expf(a0.z); Ac[3]=-__expf(a0.w);
    Ac[4]=-__expf(a1.x); Ac[5]=-__expf(a1.y); Ac[6]=-__expf(a1.z); Ac[7]=-__expf(a1.w);
    Ac[8]=-__expf(a2.x); Ac[9]=-__expf(a2.y); Ac[10]=-__expf(a2.z); Ac[11]=-__expf(a2.w);
    Ac[12]=-__expf(a3.x); Ac[13]=-__expf(a3.y); Ac[14]=-__expf(a3.z); Ac[15]=-__expf(a3.w);
  }

  float p[16], h[16];
#pragma unroll
  for (int s = 0; s < 16; ++s) { p[s] = 1.f; h[s] = 0.f; }

  for (int l = 0; l < CH; ++l) {
    float dtv = bf2f(dtb[(tok0 + l) * 2048 + d]);
    float uv  = bf2f(xcb[(tok0 + l) * 2048 + d]);
    float du  = dtv * uv;
    float Bv[16];
#pragma unroll
    for (int j = 0; j < 4; ++j) {
      float4 bb = *(const float4*)(xd + l * 96 + 64 + j * 4);
      Bv[j*4+0]=bb.x; Bv[j*4+1]=bb.y; Bv[j*4+2]=bb.z; Bv[j*4+3]=bb.w;
    }
#pragma unroll
    for (int s = 0; s < 16; ++s) {
      float dA = __expf(dtv * Ac[s]);
      p[s] *= dA;
      h[s] = fmaf(dA, h[s], du * Bv[s]);
    }
  }

  float* pp = PH + (size_t)t * 16;
#pragma unroll
  for (int j = 0; j < 4; ++j) {
    *(float4*)(pp + j * 4)       = make_float4(p[j*4], p[j*4+1], p[j*4+2], p[j*4+3]);
    *(float4*)(pp + PHN + j * 4) = make_float4(h[j*4], h[j*4+1], h[j*4+2], h[j*4+3]);
  }
}

// Sequential fix-up over chunks: overwrite Hl[c] with chunk-entry state hin[c].
__global__ __launch_bounds__(256) void scan_fix(float* __restrict__ PH)
{
  int tid = blockIdx.x * 256 + threadIdx.x;  // (b*2048+d)*16+s
  int s = tid & 15;
  int d = (tid >> 4) & 2047;
  int b = tid >> 15;
  float h = 0.f;
  for (int c = 0; c < NCHK; ++c) {
    size_t idx = ((((size_t)(b * NCHK + c) * 2048) + d) * 16) + s;
    float p  = PH[idx];
    float hl = PH[idx + PHN];
    PH[idx + PHN] = h;               // hin for chunk c
    h = fmaf(p, h, hl);
  }
}

__global__ __launch_bounds__(256) void scan_p2(
    const float* __restrict__ A_log, const float* __restrict__ Dvec,
    const float* __restrict__ x_dbl, const unsigned short* __restrict__ xcb,
    const unsigned short* __restrict__ xzb, const float* __restrict__ PH,
    const unsigned short* __restrict__ dtb, unsigned short* __restrict__ ybf)
{
  const int t = blockIdx.x * 256 + threadIdx.x;
  const int d = t & 2047;
  const int c = (t >> 11) & (NCHK - 1);
  const int b = t >> 17;
  const size_t tok0 = (size_t)b * SEQ + c * CH;
  const float* xd = x_dbl + tok0 * 96;
  const float Dd = Dvec[d];

  float Ac[16];
  {
    float4 a0 = *(const float4*)(A_log + d * 16);
    float4 a1 = *(const float4*)(A_log + d * 16 + 4);
    float4 a2 = *(const float4*)(A_log + d * 16 + 8);
    float4 a3 = *(const float4*)(A_log + d * 16 + 12);
    Ac[0]=-__expf(a0.x); Ac[1]=-__expf(a0.y); Ac[2]=-__expf(a0.z); Ac[3]=-__expf(a0.w);
    Ac[4]=-__expf(a1.x); Ac[5]=-__expf(a1.y); Ac[6]=-__expf(a1.z); Ac[7]=-__expf(a1.w);
    Ac[8]=-__expf(a2.x); Ac[9]=-__expf(a2.y); Ac[10]=-__expf(a2.z); Ac[11]=-__expf(a2.w);
    Ac[12]=-__expf(a3.x); Ac[13]=-__expf(a3.y); Ac[14]=-__expf(a3.z); Ac[15]=-__expf(a3.w);
  }

  const float* pp = PH + (size_t)t * 16;
  float h[16];
#pragma unroll
  for (int j = 0; j < 4; ++j) {
    float4 hh = *(const float4*)(pp + PHN + j * 4);
    h[j*4+0]=hh.x; h[j*4+1]=hh.y; h[j*4+2]=hh.z; h[j*4+3]=hh.w;
  }

  for (int l = 0; l < CH; ++l) {
    float dtv = bf2f(dtb[(tok0 + l) * 2048 + d]);
    float uv  = bf2f(xcb[(tok0 + l) * 2048 + d]);
    float zv  = bf2f(xzb[(tok0 + l) * 4096 + 2048 + d]);
    float du  = dtv * uv;
    float Bv[16], Cv[16];
#pragma unroll
    for (int j = 0; j < 4; ++j) {
      float4 bb = *(const float4*)(xd + l * 96 + 64 + j * 4);
      float4 cc = *(const float4*)(xd + l * 96 + 80 + j * 4);
      Bv[j*4+0]=bb.x; Bv[j*4+1]=bb.y; Bv[j*4+2]=bb.z; Bv[j*4+3]=bb.w;
      Cv[j*4+0]=cc.x; Cv[j*4+1]=cc.y; Cv[j*4+2]=cc.z; Cv[j*4+3]=cc.w;
    }
    float y = 0.f;
#pragma unroll
    for (int s = 0; s < 16; ++s) {
      float dA = __expf(dtv * Ac[s]);
      h[s] = fmaf(dA, h[s], du * Bv[s]);
      y = fmaf(h[s], Cv[s], y);
    }
    y = fmaf(Dd, uv, y);
    y *= zv / (1.f + __expf(-zv));
    ybf[(tok0 + l) * 2048 + d] = f2bf(y);
  }
}

// ---------------------------------------------------------------------------
// Fused: v = p0 + p1 + x  (out_proj split-K reduce + residual), then LN.
// ---------------------------------------------------------------------------
__global__ __launch_bounds__(256) void ln2_k(
    const float* __restrict__ p0, const float* __restrict__ p1,
    const float* __restrict__ x, const float* __restrict__ g,
    const float* __restrict__ bb, float* __restrict__ out)
{
  int row = blockIdx.x;
  size_t off = (size_t)row * 1024;
  float4 a = ((const float4*)(p0 + off))[threadIdx.x];
  float4 b = ((const float4*)(p1 + off))[threadIdx.x];
  float4 c = ((const float4*)(x  + off))[threadIdx.x];
  float4 v;
  v.x = a.x + b.x + c.x; v.y = a.y + b.y + c.y;
  v.z = a.z + b.z + c.z; v.w = a.w + b.w + c.w;
  float s  = v.x + v.y + v.z + v.w;
  float sq = v.x * v.x + v.y * v.y + v.z * v.z + v.w * v.w;
#pragma unroll
  for (int o = 32; o >= 1; o >>= 1) {
    s  += __shfl_xor(s,  o, 64);
    sq += __shfl_xor(sq, o, 64);
  }
  __shared__ float red[8];
  int wid = threadIdx.x >> 6;
  if ((threadIdx.x & 63) == 0) { red[wid] = s; red[4 + wid] = sq; }
  __syncthreads();
  s  = red[0] + red[1] + red[2] + red[3];
  sq = red[4] + red[5] + red[6] + red[7];
  float mu  = s * (1.f / 1024.f);
  float var = sq * (1.f / 1024.f) - mu * mu;
  float r   = rsqrtf(var + 1e-5f);
  int col = threadIdx.x * 4;
  float4 gv = *(const float4*)(g + col);
  float4 bv = *(const float4*)(bb + col);
  float4 o;
  o.x = (v.x - mu) * r * gv.x + bv.x;
  o.y = (v.y - mu) * r * gv.y + bv.y;
  o.z = (v.z - mu) * r * gv.z + bv.z;
  o.w = (v.w - mu) * r * gv.w + bv.w;
  ((float4*)(out + off))[threadIdx.x] = o;
}

// ---------------------------------------------------------------------------
extern "C" void kernel_launch(void* const* d_in, const int* in_sizes, int n_in,
                              void* d_out, int out_size, void* d_ws, size_t ws_size,
                              hipStream_t stream)
{
  const float* x       = (const float*)d_in[0];
  const float* in_proj = (const float*)d_in[1];
  const float* conv_w  = (const float*)d_in[2];
  const float* conv_b  = (const float*)d_in[3];
  const float* x_proj  = (const float*)d_in[4];
  const float* dt_w    = (const float*)d_in[5];
  const float* dt_b    = (const float*)d_in[6];
  const float* A_log   = (const float*)d_in[7];
  const float* Dv      = (const float*)d_in[8];
  const float* out_w   = (const float*)d_in[9];
  const float* ln_g    = (const float*)d_in[10];
  const float* ln_bias = (const float*)d_in[11];
  float* out = (float*)d_out;

  char* w8 = (char*)d_ws;
  unsigned short* xz_bf = (unsigned short*)(w8 + 0);           // 33.55 MB
  unsigned short* xc_bf = (unsigned short*)(w8 + 33554432);    // 16.78 MB
  float*          xdbl  = (float*)(w8 + 50331648);             //  1.57 MB
  unsigned short* dty   = (unsigned short*)(w8 + 51904512);    // 16.78 MB (bf16 dt)
  unsigned short* y_bf  = (unsigned short*)(w8 + 68681728);    // 16.78 MB
  unsigned short* x_bf  = (unsigned short*)(w8 + 85458944);    //  8.39 MB (also dtr later)
  unsigned short* w_in  = (unsigned short*)(w8 + 93847552);    //  8.39 MB
  unsigned short* w_x   = (unsigned short*)(w8 + 102236160);   //  0.38 MB
  unsigned short* w_dt  = (unsigned short*)(w8 + 102629376);   //  0.26 MB
  unsigned short* w_out = (unsigned short*)(w8 + 102891520);   //  4.19 MB
  float*          pbufx = (float*)(w8 + 107085824);            // 12.58 MB
  float*          PH    = (float*)(w8 + 119668736);            // 33.55 MB
  float*          pbufo = (float*)xz_bf;                       // alias (exact fit)

  dim3 blk(256);
  // 0) all fp32->bf16 casts in one dispatch
  cast5_k<<<dim3((N_ALL / 4 + 255) / 256), blk, 0, stream>>>(
      x, x_bf, in_proj, w_in, x_proj, w_x, dt_w, w_dt, out_w, w_out);
  // 1) in_proj MFMA -> xz_bf (bf16 out)
  mgemm<3><<<dim3(32, 32, 1), blk, 0, stream>>>(x_bf, 1024, w_in, 1024,
                                                xz_bf, 4096, 4096, 1024, nullptr, 0);
  // 2) conv + silu -> xc_bf
  conv_silu_k<<<dim3((NTOK * D_INNER / 4) / 256), blk, 0, stream>>>(
      xz_bf, conv_w, conv_b, xc_bf);
  // 3) x_proj MFMA, split-K=8 -> partials; fused reduce + dt_r cast into x_bf
  mgemm<0><<<dim3(1, 32, 8), blk, 0, stream>>>(xc_bf, 2048, w_x, 2048,
                                               pbufx, 96, 96, 256, nullptr,
                                               (size_t)4096 * 96);
  redcast_k<<<dim3(4096 * 96 / 1024), blk, 0, stream>>>(pbufx, xdbl, x_bf /*dtr*/);
  // 4) dt_proj + softplus via MFMA (K=64) -> bf16 dt
  mgemm<1><<<dim3(16, 32, 1), blk, 0, stream>>>(x_bf /*dtr*/, 64, w_dt, 64,
                                                dty, 2048, 2048, 64, dt_b, 0);
  // 5) chunked selective scan -> y_bf
  scan_p1 <<<dim3(BSZ * NCHK * 2048 / 256), blk, 0, stream>>>(A_log, xdbl, xc_bf, dty, PH);
  scan_fix<<<dim3(BSZ * 2048 * 16 / 256), blk, 0, stream>>>(PH);
  scan_p2 <<<dim3(BSZ * NCHK * 2048 / 256), blk, 0, stream>>>(A_log, Dv, xdbl, xc_bf,
                                                              xz_bf, PH, dty, y_bf);
  // 6) out_proj MFMA, split-K=2 -> partials in pbufo (xz_bf dead after scan_p2)
  mgemm<0><<<dim3(8, 32, 2), blk, 0, stream>>>(y_bf, 2048, w_out, 2048,
                                               pbufo, 1024, 1024, 1024, nullptr,
                                               (size_t)4096 * 1024);
  // 7) fused reduce + residual + layernorm -> out
  ln2_k<<<dim3(NTOK), blk, 0, stream>>>(pbufo, pbufo + (size_t)4096 * 1024,
                                        x, ln_g, ln_bias, out);
}